// Round 9
// baseline (1191.463 us; speedup 1.0000x reference)
//
#include <hip/hip_runtime.h>
#include <hip/hip_bf16.h>
#include <math.h>

using short8 = __attribute__((ext_vector_type(8))) short;
using f32x4  = __attribute__((ext_vector_type(4))) float;

#define MFMA_B16(A,B,C) __builtin_amdgcn_mfma_f32_16x16x32_bf16((A),(B),(C),0,0,0)

__device__ __forceinline__ unsigned short f2bfu(float x) {   // RNE f32->bf16
  unsigned u = __float_as_uint(x);
  return (unsigned short)((u + 0x7fffu + ((u >> 16) & 1u)) >> 16);
}
__device__ __forceinline__ unsigned pk2(float a, float b) {
  return (unsigned)f2bfu(a) | ((unsigned)f2bfu(b) << 16);
}

// Repack f32 [rows][K] -> bf16 fragment order [tile][kc][r16][8].
__global__ void cvt_pack(const float* __restrict__ src, unsigned short* __restrict__ dst,
                         int K, int n) {
  int K8 = K >> 3;
  int i = blockIdx.x * blockDim.x + threadIdx.x;
  if (i >= n) return;
  int e = i & 7;
  int idx = i >> 3;
  int r = idx & 15; idx >>= 4;
  int kc = idx % K8, ci = idx / K8;
  dst[i] = f2bfu(src[(size_t)(ci * 16 + r) * K + kc * 8 + e]);
}

// token-row base (in floats) for window-major row index m = w*49 + r
__device__ __forceinline__ int gmapbase(int m) {
  int w = m / 49, r = m - w * 49;
  int iw = w & 7, ih = (w >> 3) & 7, bt = w >> 6;
  int wi = r / 7, wj = r - wi * 7;
  return (bt * 3136 + (ih * 7 + wi) * 56 + iw * 7 + wj) * 384;
}

// LayerNorm of 64 window-major rows -> bf16 dst[m][384]. 8 lanes/row, 512 thr.
__device__ __forceinline__ void ln_rows(const float* __restrict__ src,
                                        const float* __restrict__ gw,
                                        const float* __restrict__ gb,
                                        unsigned short* __restrict__ dst,
                                        int m0, int tid) {
  int m = m0 + (tid >> 3), lj = tid & 7;
  size_t gbase = (size_t)gmapbase(m);
  float4 xv[12];
  float sx = 0.f, sxx = 0.f;
  #pragma unroll
  for (int k = 0; k < 12; ++k) {
    xv[k] = *(const float4*)&src[gbase + (lj + 8*k) * 4];
    sx  += xv[k].x + xv[k].y + xv[k].z + xv[k].w;
    sxx += xv[k].x*xv[k].x + xv[k].y*xv[k].y + xv[k].z*xv[k].z + xv[k].w*xv[k].w;
  }
  #pragma unroll
  for (int d = 1; d < 8; d <<= 1) { sx += __shfl_xor(sx, d, 8); sxx += __shfl_xor(sxx, d, 8); }
  float mean = sx * (1.f/384.f);
  float rs = rsqrtf(sxx * (1.f/384.f) - mean*mean + 1e-5f);
  unsigned short* drow = dst + (size_t)m * 384;
  #pragma unroll
  for (int k = 0; k < 12; ++k) {
    int c = (lj + 8*k) * 4;
    float4 gv = *(const float4*)&gw[c];
    float4 bv = *(const float4*)&gb[c];
    unsigned u0 = pk2((xv[k].x-mean)*rs*gv.x + bv.x, (xv[k].y-mean)*rs*gv.y + bv.y);
    unsigned u1 = pk2((xv[k].z-mean)*rs*gv.z + bv.z, (xv[k].w-mean)*rs*gv.w + bv.w);
    *(uint2*)&drow[c] = make_uint2(u0, u1);
  }
}

__global__ __launch_bounds__(512)
void ln1_k(const float* __restrict__ tokens, const float* __restrict__ g,
           const float* __restrict__ b, unsigned short* __restrict__ aln) {
  ln_rows(tokens, g, b, aln, blockIdx.x * 64, threadIdx.x);
}

// ---- shared GEMM helpers: 64-row A tile in LDS, XOR-swizzled vs 768B stride ----
__device__ __forceinline__ void stageA(const unsigned short* __restrict__ gsrc,
                                       size_t gelem0, char* lds, int tid) {
  for (int i = tid; i < 64 * 48; i += 512) {
    int row = i / 48, c = i - row * 48;
    short8 v = *(const short8*)(gsrc + gelem0 + (size_t)row * 384 + c * 8);
    int boff = (row * 768 + c * 16) ^ ((row & 7) << 4);
    *(short8*)(lds + boff) = v;
  }
}
__device__ __forceinline__ short8 ldsA(const char* lds, int row, int k0) {
  int boff = (row * 768 + k0 * 2) ^ ((row & 7) << 4);
  return *(const short8*)(lds + boff);
}
__device__ __forceinline__ short8 ldW(const unsigned short* wp, int tile, int K8,
                                      int kcb, int l) {
  return *(const short8*)(wp + (((size_t)(tile * K8 + kcb)) << 7) + l * 8);
}

// K3: qkv[m][1152] = aln @ ipw^T + bias (q scaled). grid (784, 3=part), 512 thr.
__global__ __launch_bounds__(512, 4)
void qkv_gemm(const unsigned short* __restrict__ aln, const unsigned short* __restrict__ wp,
              const float* __restrict__ ipb, unsigned short* __restrict__ qkv) {
  extern __shared__ char lds[];
  const int tid = threadIdx.x;
  const int m0 = blockIdx.x * 64, part = blockIdx.y;
  stageA(aln, (size_t)m0 * 384, lds, tid);
  __syncthreads();
  const int l = tid & 63, wv = tid >> 6, cl = l & 15, kg = l >> 4;
  const int rt = wv & 3, ch = wv >> 2;
  f32x4 acc[12];
  #pragma unroll
  for (int j = 0; j < 12; ++j) acc[j] = f32x4{0.f,0.f,0.f,0.f};
  for (int kt = 0; kt < 12; ++kt) {
    int k0 = kt * 32 + kg * 8;
    short8 a = ldsA(lds, rt * 16 + cl, k0);
    #pragma unroll
    for (int j = 0; j < 12; ++j) {
      short8 bf = ldW(wp, part * 24 + ch * 12 + j, 48, kt * 4, l);
      acc[j] = MFMA_B16(a, bf, acc[j]);
    }
  }
  float scl = (part == 0) ? 0.17677669529663687f : 1.f;
  #pragma unroll
  for (int j = 0; j < 12; ++j) {
    int wcol = (ch * 12 + j) * 16 + cl;
    float bias = ipb[part * 384 + wcol];
    #pragma unroll
    for (int rg = 0; rg < 4; ++rg) {
      int m = m0 + rt * 16 + kg * 4 + rg;
      qkv[(size_t)m * 1152 + part * 384 + wcol] = f2bfu((acc[j][rg] + bias) * scl);
    }
  }
}

// K4: per-window attention. 1024 blocks, 256 thr (wave = q col-tile).
__global__ __launch_bounds__(256, 4)
void attn_k(const unsigned short* __restrict__ qkv, unsigned short* __restrict__ oh) {
  __shared__ unsigned short vT2[32 * 56];
  const int tid = threadIdx.x;
  const int l = tid & 63, wv = tid >> 6;
  const int cl = l & 15, kg = l >> 4;
  const size_t base = (size_t)blockIdx.x * 49;
  for (int i = tid; i < 224; i += 256) vT2[(i / 7) * 56 + 49 + i % 7] = 0;
  const int qrow = (16 * wv + cl < 49) ? 16 * wv + cl : 48;
  for (int h = 0; h < 12; ++h) {
    __syncthreads();
    for (int i = tid; i < 1568; i += 256) {       // stage V^T for this head
      int r = i >> 5, d = i & 31;
      vT2[d * 56 + r] = qkv[(base + r) * 1152 + 768 + h * 32 + d];
    }
    __syncthreads();
    short8 bq = *(const short8*)(qkv + (base + qrow) * 1152 + h * 32 + kg * 8);
    f32x4 dsc[4];
    #pragma unroll
    for (int kri = 0; kri < 4; ++kri) {
      size_t mk = base + 16 * kri + cl;
      if (mk > 50175) mk = 50175;
      short8 ak = *(const short8*)(qkv + mk * 1152 + 384 + h * 32 + kg * 8);
      f32x4 z{0.f,0.f,0.f,0.f};
      dsc[kri] = MFMA_B16(ak, bq, z);
    }
    float ev[4][4];
    float mx = -1e30f;
    #pragma unroll
    for (int kri = 0; kri < 4; ++kri)
      #pragma unroll
      for (int r = 0; r < 4; ++r) {
        int kidx = 16 * kri + 4 * kg + r;
        float v = (kidx < 49) ? dsc[kri][r] : -1e30f;
        ev[kri][r] = v;
        mx = fmaxf(mx, v);
      }
    mx = fmaxf(mx, __shfl_xor(mx, 16));
    mx = fmaxf(mx, __shfl_xor(mx, 32));
    float sum = 0.f;
    #pragma unroll
    for (int kri = 0; kri < 4; ++kri)
      #pragma unroll
      for (int r = 0; r < 4; ++r) {
        float e = __expf(ev[kri][r] - mx);
        ev[kri][r] = e; sum += e;
      }
    sum += __shfl_xor(sum, 16);
    sum += __shfl_xor(sum, 32);
    float inv = 1.f / sum;
    unsigned pk[4][2];
    #pragma unroll
    for (int kri = 0; kri < 4; ++kri) {
      pk[kri][0] = pk2(ev[kri][0] * inv, ev[kri][1] * inv);
      pk[kri][1] = pk2(ev[kri][2] * inv, ev[kri][3] * inv);
    }
    f32x4 dot0{0.f,0.f,0.f,0.f}, dot1{0.f,0.f,0.f,0.f};
    const int sA = cl + 32 * (kg & 1);
    const bool hi = (kg >> 1) & 1;
    #pragma unroll
    for (int kt = 0; kt < 2; ++kt) {
      unsigned x0 = (unsigned)__shfl((int)pk[2*kt][0],   sA);
      unsigned x1 = (unsigned)__shfl((int)pk[2*kt][1],   sA);
      unsigned x2 = (unsigned)__shfl((int)pk[2*kt][0],   sA + 16);
      unsigned x3 = (unsigned)__shfl((int)pk[2*kt][1],   sA + 16);
      unsigned y0 = (unsigned)__shfl((int)pk[2*kt+1][0], sA);
      unsigned y1 = (unsigned)__shfl((int)pk[2*kt+1][1], sA);
      unsigned y2 = (unsigned)__shfl((int)pk[2*kt+1][0], sA + 16);
      unsigned y3 = (unsigned)__shfl((int)pk[2*kt+1][1], sA + 16);
      uint4 bu = make_uint4(hi ? y0 : x0, hi ? y1 : x1, hi ? y2 : x2, hi ? y3 : x3);
      short8 bfrag = *(short8*)&bu;
      short8 a0 = *(const short8*)&vT2[(cl     ) * 56 + kt * 32 + kg * 8];
      short8 a1 = *(const short8*)&vT2[(16 + cl) * 56 + kt * 32 + kg * 8];
      dot0 = MFMA_B16(a0, bfrag, dot0);
      dot1 = MFMA_B16(a1, bfrag, dot1);
    }
    int q = 16 * wv + cl;
    if (q < 49) {
      size_t ob = (base + q) * 384 + h * 32 + kg * 4;
      *(unsigned*)(oh + ob     ) = pk2(dot0[0], dot0[1]);
      *(unsigned*)(oh + ob + 2 ) = pk2(dot0[2], dot0[3]);
      *(unsigned*)(oh + ob + 16) = pk2(dot1[0], dot1[1]);
      *(unsigned*)(oh + ob + 18) = pk2(dot1[2], dot1[3]);
    }
  }
}

// K5: win = oh @ outw^T + outb + tokens -> d_out; then LN2 -> aln2. grid 784.
__global__ __launch_bounds__(512, 4)
void outproj_k(const unsigned short* __restrict__ oh, const unsigned short* __restrict__ wp,
               const float* __restrict__ outb, const float* __restrict__ tokens,
               const float* __restrict__ ln2g, const float* __restrict__ ln2b,
               float* __restrict__ dout, unsigned short* __restrict__ aln2) {
  extern __shared__ char lds[];
  const int tid = threadIdx.x;
  const int m0 = blockIdx.x * 64;
  stageA(oh, (size_t)m0 * 384, lds, tid);
  __syncthreads();
  const int l = tid & 63, wv = tid >> 6, cl = l & 15, kg = l >> 4;
  const int rt = wv & 3, ch = wv >> 2;
  f32x4 acc[12];
  #pragma unroll
  for (int j = 0; j < 12; ++j) acc[j] = f32x4{0.f,0.f,0.f,0.f};
  for (int kt = 0; kt < 12; ++kt) {
    int k0 = kt * 32 + kg * 8;
    short8 a = ldsA(lds, rt * 16 + cl, k0);
    #pragma unroll
    for (int j = 0; j < 12; ++j) {
      short8 bf = ldW(wp, ch * 12 + j, 48, kt * 4, l);
      acc[j] = MFMA_B16(a, bf, acc[j]);
    }
  }
  int gb[4];
  #pragma unroll
  for (int rg = 0; rg < 4; ++rg) gb[rg] = gmapbase(m0 + rt * 16 + kg * 4 + rg);
  #pragma unroll
  for (int j = 0; j < 12; ++j) {
    int col = (ch * 12 + j) * 16 + cl;
    float ob = outb[col];
    #pragma unroll
    for (int rg = 0; rg < 4; ++rg)
      dout[gb[rg] + col] = tokens[gb[rg] + col] + acc[j][rg] + ob;
  }
  __syncthreads();   // drains vmcnt; this block wrote ALL cols of its 64 rows
  ln_rows(dout, ln2g, ln2b, aln2, m0, tid);
}

// K7: MLP fused: hid chunk in LDS, MLP2 accumulated in regs. grid 784.
__global__ __launch_bounds__(512, 4)
void mlp_fused(const unsigned short* __restrict__ aln2, const unsigned short* __restrict__ w1p,
               const float* __restrict__ b1, const unsigned short* __restrict__ w2p,
               const float* __restrict__ b2, float* __restrict__ dout) {
  extern __shared__ char lds[];                 // [0,49152): A ; [49152,66560): hid
  unsigned short* hid = (unsigned short*)(lds + 49152);
  const int tid = threadIdx.x;
  const int m0 = blockIdx.x * 64;
  stageA(aln2, (size_t)m0 * 384, lds, tid);
  __syncthreads();
  const int l = tid & 63, wv = tid >> 6, cl = l & 15, kg = l >> 4;
  const int rt = wv & 3, ch = wv >> 2;
  f32x4 macc[12];
  #pragma unroll
  for (int j = 0; j < 12; ++j) macc[j] = f32x4{0.f,0.f,0.f,0.f};
  for (int cc = 0; cc < 12; ++cc) {
    f32x4 e[4];
    #pragma unroll
    for (int jj = 0; jj < 4; ++jj) e[jj] = f32x4{0.f,0.f,0.f,0.f};
    for (int kt = 0; kt < 12; ++kt) {
      int k0 = kt * 32 + kg * 8;
      short8 a = ldsA(lds, rt * 16 + cl, k0);
      #pragma unroll
      for (int jj = 0; jj < 4; ++jj) {
        short8 bf = ldW(w1p, cc * 8 + ch * 4 + jj, 48, kt * 4, l);
        e[jj] = MFMA_B16(a, bf, e[jj]);
      }
    }
    #pragma unroll
    for (int jj = 0; jj < 4; ++jj) {
      int hcol = (ch * 4 + jj) * 16 + cl;
      float bb = b1[cc * 128 + hcol];
      #pragma unroll
      for (int rg = 0; rg < 4; ++rg) {
        int row = rt * 16 + kg * 4 + rg;
        float x = e[jj][rg] + bb;
        // gelu(x) ~= x * sigmoid(1.5957691(x + 0.044715 x^3))
        float t2 = 0.044715f * x * x;
        float arg = __builtin_fmaf(t2, x, x);
        float ex = __expf(1.5957691216f * arg);
        hid[row * 136 + hcol] = f2bfu(x * (ex / (ex + 1.f)));
      }
    }
    __syncthreads();
    #pragma unroll
    for (int kt2 = 0; kt2 < 4; ++kt2) {
      int k0 = kt2 * 32 + kg * 8;
      short8 hd = *(const short8*)&hid[(rt * 16 + cl) * 136 + k0];
      #pragma unroll
      for (int j = 0; j < 12; ++j) {
        short8 bf = ldW(w2p, ch * 12 + j, 192, cc * 16 + kt2 * 4, l);
        macc[j] = MFMA_B16(hd, bf, macc[j]);
      }
    }
    __syncthreads();
  }
  int gb[4];
  #pragma unroll
  for (int rg = 0; rg < 4; ++rg) gb[rg] = gmapbase(m0 + rt * 16 + kg * 4 + rg);
  #pragma unroll
  for (int j = 0; j < 12; ++j) {
    int col = (ch * 12 + j) * 16 + cl;
    float bb2 = b2[col];
    #pragma unroll
    for (int rg = 0; rg < 4; ++rg)
      dout[gb[rg] + col] = dout[gb[rg] + col] + macc[j][rg] + bb2;
  }
}

// ================= fused fallback (round-8 kernel, known-pass) =================
#define ALN_STR 392
#define ALN_SZ  38416
#define POOL    76832
#define PS      34816
#define Q2_OFF  0
#define K2_OFF  7056
#define VT_OFF  14112
#define OH_OFF  23328
#define HIDB    17408
#define QK_STR  72
#define VT_STR  72
#define OH_STR  72
#define HID_STR 136
#define SMEM_BYTES 146464

template<bool WBF>
__device__ __forceinline__ short8 loadW(const void* base, int tile, int K8, int kcb,
                                        int l, int row, int ldk, int k0) {
  if constexpr (WBF) {
    return *(const short8*)((const unsigned short*)base +
                            (((size_t)(tile * K8 + kcb)) << 7) + l * 8);
  } else {
    const float* p = (const float*)base + (size_t)row * ldk + k0;
    float4 x = *(const float4*)p;
    float4 y = *(const float4*)(p + 4);
    short8 r;
    r[0]=(short)f2bfu(x.x); r[1]=(short)f2bfu(x.y); r[2]=(short)f2bfu(x.z); r[3]=(short)f2bfu(x.w);
    r[4]=(short)f2bfu(y.x); r[5]=(short)f2bfu(y.y); r[6]=(short)f2bfu(y.z); r[7]=(short)f2bfu(y.w);
    return r;
  }
}

template<bool WBF>
__global__ __launch_bounds__(1024, 4)
void swin_mfma(const float* __restrict__ tokens,
               const void* __restrict__ ipw,  const float* __restrict__ ipb,
               const void* __restrict__ outw, const float* __restrict__ outb,
               const float* __restrict__ ln1g, const float* __restrict__ ln1b,
               const void* __restrict__ w1,   const float* __restrict__ b1,
               const void* __restrict__ w2,   const float* __restrict__ b2,
               const float* __restrict__ ln2g, const float* __restrict__ ln2b,
               float* __restrict__ out)
{
  extern __shared__ char smem[];
  const int tid = threadIdx.x;
  const int win = tid >> 9;
  const int gw  = tid >> 6;
  const int wv  = gw & 7;
  const int l   = tid & 63;
  const int cl  = l & 15, kg = l >> 4;

  unsigned short* alnW[2]; char* poolW[2];
  #pragma unroll
  for (int w = 0; w < 2; ++w) {
    alnW[w]  = (unsigned short*)(smem + w * ALN_SZ);
    poolW[w] = smem + POOL + w * PS;
  }
  unsigned short* aln = alnW[win];
  char* pool = poolW[win];
  unsigned short* q2  = (unsigned short*)(pool + Q2_OFF);
  unsigned short* k2  = (unsigned short*)(pool + K2_OFF);
  unsigned short* vT2 = (unsigned short*)(pool + VT_OFF);
  unsigned short* oh  = (unsigned short*)(pool + OH_OFF);

  const int wid0 = blockIdx.x * 2;
  auto gidxw = [&](int w, int r, int c) -> size_t {
    int wid = wid0 + w;
    int iw = wid & 7, ih = (wid >> 3) & 7, bt = wid >> 6;
    int wi = r / 7, wj = r - wi * 7;
    return ((size_t)bt * 3136 + (size_t)((ih*7 + wi) * 56 + iw*7 + wj)) * 384 + c;
  };

  auto ln_pass = [&](const float* src, const float* gw_, const float* gb_) {
    int row = (tid >> 3) & 63, lj = tid & 7;
    if (row < 49) {
      size_t base = gidxw(win, row, 0);
      float4 xv[12];
      float sx = 0.f, sxx = 0.f;
      #pragma unroll
      for (int k = 0; k < 12; ++k) {
        xv[k] = *(const float4*)&src[base + (lj + 8*k) * 4];
        sx  += xv[k].x + xv[k].y + xv[k].z + xv[k].w;
        sxx += xv[k].x*xv[k].x + xv[k].y*xv[k].y + xv[k].z*xv[k].z + xv[k].w*xv[k].w;
      }
      #pragma unroll
      for (int d = 1; d < 8; d <<= 1) { sx += __shfl_xor(sx, d, 8); sxx += __shfl_xor(sxx, d, 8); }
      float mean = sx * (1.f/384.f);
      float rs = rsqrtf(sxx * (1.f/384.f) - mean*mean + 1e-5f);
      unsigned short* arow = aln + row * ALN_STR;
      #pragma unroll
      for (int k = 0; k < 12; ++k) {
        int c = (lj + 8*k) * 4;
        float4 gv = *(const float4*)&gw_[c];
        float4 bv = *(const float4*)&gb_[c];
        unsigned u0 = pk2((xv[k].x-mean)*rs*gv.x + bv.x, (xv[k].y-mean)*rs*gv.y + bv.y);
        unsigned u1 = pk2((xv[k].z-mean)*rs*gv.z + bv.z, (xv[k].w-mean)*rs*gv.w + bv.w);
        *(uint2*)&arow[c] = make_uint2(u0, u1);
      }
    }
  };

  const int ri = gw & 3;
  const int cg = gw >> 2;
  const int arowA = (cl + 16 * ri) * ALN_STR;

  auto qkv = [&](int pr) {
    int tile[3], grow[3], part[3], wt[3];
    #pragma unroll
    for (int j = 0; j < 3; ++j) {
      int ci = cg * 3 + j;
      part[j] = ci >> 2; wt[j] = ci & 3;
      tile[j] = part[j] * 24 + pr * 4 + wt[j];
      grow[j] = part[j] * 384 + pr * 64 + wt[j] * 16 + cl;
    }
    f32x4 d00{0,0,0,0}, d01{0,0,0,0}, d02{0,0,0,0};
    f32x4 d10{0,0,0,0}, d11{0,0,0,0}, d12{0,0,0,0};
    #pragma unroll
    for (int kt = 0; kt < 12; ++kt) {
      int k0 = kt * 32 + kg * 8;
      short8 wb0 = loadW<WBF>(ipw, tile[0], 48, kt*4, l, grow[0], 384, k0);
      short8 wb1 = loadW<WBF>(ipw, tile[1], 48, kt*4, l, grow[1], 384, k0);
      short8 wb2 = loadW<WBF>(ipw, tile[2], 48, kt*4, l, grow[2], 384, k0);
      short8 a0 = *(const short8*)&alnW[0][arowA + k0];
      short8 a1 = *(const short8*)&alnW[1][arowA + k0];
      d00 = MFMA_B16(a0, wb0, d00); d01 = MFMA_B16(a0, wb1, d01); d02 = MFMA_B16(a0, wb2, d02);
      d10 = MFMA_B16(a1, wb0, d10); d11 = MFMA_B16(a1, wb1, d11); d12 = MFMA_B16(a1, wb2, d12);
    }
    #pragma unroll
    for (int w = 0; w < 2; ++w) {
      unsigned short* q2w = (unsigned short*)(poolW[w] + Q2_OFF);
      unsigned short* k2w = (unsigned short*)(poolW[w] + K2_OFF);
      unsigned short* vTw = (unsigned short*)(poolW[w] + VT_OFF);
      #pragma unroll
      for (int j = 0; j < 3; ++j) {
        f32x4 dd = (w == 0) ? (j == 0 ? d00 : j == 1 ? d01 : d02)
                            : (j == 0 ? d10 : j == 1 ? d11 : d12);
        float bias = ipb[grow[j]];
        float scl = (part[j] == 0) ? 0.17677669529663687f : 1.f;
        int within = wt[j] * 16 + cl;
        #pragma unroll
        for (int rg = 0; rg < 4; ++rg) {
          int row = kg * 4 + rg + 16 * ri;
          if (row < 49) {
            unsigned short bv = f2bfu((dd[rg] + bias) * scl);
            if      (part[j] == 0) q2w[row * QK_STR + within] = bv;
            else if (part[j] == 1) k2w[row * QK_STR + within] = bv;
            else                   vTw[within * VT_STR + row] = bv;
          }
        }
      }
    }
  };

  for (int i = (tid & 511); i < (64*VT_STR)/2; i += 512)
    ((unsigned*)(pool + VT_OFF))[i] = 0u;
  ln_pass(tokens, ln1g, ln1b);
  __syncthreads();

  f32x4 opacc[2][6];
  #pragma unroll
  for (int a = 0; a < 2; ++a)
    #pragma unroll
    for (int b = 0; b < 6; ++b) opacc[a][b] = f32x4{0.f,0.f,0.f,0.f};

  qkv(0);
  __syncthreads();

  const int hl = wv & 1, qci = wv >> 1;

  for (int pr = 0; pr < 6; ++pr) {
    {
      short8 bq = *(const short8*)&q2[(16*qci + cl) * QK_STR + hl*32 + kg*8];
      f32x4 dsc[4];
      #pragma unroll
      for (int kri = 0; kri < 4; ++kri) {
        short8 ak = *(const short8*)&k2[(16*kri + cl) * QK_STR + hl*32 + kg*8];
        f32x4 z{0.f,0.f,0.f,0.f};
        dsc[kri] = MFMA_B16(ak, bq, z);
      }
      float ev[4][4];
      float mx = -1e30f;
      #pragma unroll
      for (int kri = 0; kri < 4; ++kri)
        #pragma unroll
        for (int r = 0; r < 4; ++r) {
          int kidx = 16*kri + 4*kg + r;
          float v = (kidx < 49) ? dsc[kri][r] : -1e30f;
          ev[kri][r] = v;
          mx = fmaxf(mx, v);
        }
      mx = fmaxf(mx, __shfl_xor(mx, 16));
      mx = fmaxf(mx, __shfl_xor(mx, 32));
      float sum = 0.f;
      #pragma unroll
      for (int kri = 0; kri < 4; ++kri)
        #pragma unroll
        for (int r = 0; r < 4; ++r) {
          float e = __expf(ev[kri][r] - mx);
          ev[kri][r] = e; sum += e;
        }
      sum += __shfl_xor(sum, 16);
      sum += __shfl_xor(sum, 32);
      float inv = 1.f / sum;
      unsigned pk[4][2];
      #pragma unroll
      for (int kri = 0; kri < 4; ++kri) {
        pk[kri][0] = pk2(ev[kri][0]*inv, ev[kri][1]*inv);
        pk[kri][1] = pk2(ev[kri][2]*inv, ev[kri][3]*inv);
      }
      f32x4 dot0{0.f,0.f,0.f,0.f}, dot1{0.f,0.f,0.f,0.f};
      const int sA = cl + 32 * (kg & 1);
      const bool hi = (kg >> 1) & 1;
      #pragma unroll
      for (int kt = 0; kt < 2; ++kt) {
        unsigned x0 = (unsigned)__shfl((int)pk[2*kt][0],   sA);
        unsigned x1 = (unsigned)__shfl((int)pk[2*kt][1],   sA);
        unsigned x2 = (unsigned)__shfl((int)pk[2*kt][0],   sA + 16);
        unsigned x3 = (unsigned)__shfl((int)pk[2*kt][1],   sA + 16);
        unsigned y0 = (unsigned)__shfl((int)pk[2*kt+1][0], sA);
        unsigned y1 = (unsigned)__shfl((int)pk[2*kt+1][1], sA);
        unsigned y2 = (unsigned)__shfl((int)pk[2*kt+1][0], sA + 16);
        unsigned y3 = (unsigned)__shfl((int)pk[2*kt+1][1], sA + 16);
        uint4 bu = make_uint4(hi ? y0 : x0, hi ? y1 : x1, hi ? y2 : x2, hi ? y3 : x3);
        short8 bfrag = *(short8*)&bu;
        short8 a0 = *(const short8*)&vT2[(hl*32 +  0 + cl) * VT_STR + kt*32 + kg*8];
        short8 a1 = *(const short8*)&vT2[(hl*32 + 16 + cl) * VT_STR + kt*32 + kg*8];
        dot0 = MFMA_B16(a0, bfrag, dot0);
        dot1 = MFMA_B16(a1, bfrag, dot1);
      }
      int q = 16*qci + cl;
      if (q < 49) {
        int base = q * OH_STR + hl*32 + kg*4;
        *(unsigned*)&oh[base     ] = pk2(dot0[0], dot0[1]);
        *(unsigned*)&oh[base +  2] = pk2(dot0[2], dot0[3]);
        *(unsigned*)&oh[base + 16] = pk2(dot1[0], dot1[1]);
        *(unsigned*)&oh[base + 18] = pk2(dot1[2], dot1[3]);
      }
    }
    __syncthreads();
    {
      short8 ao[2][2];
      #pragma unroll
      for (int w = 0; w < 2; ++w) {
        unsigned short* ohw = (unsigned short*)(poolW[w] + OH_OFF);
        ao[w][0] = *(const short8*)&ohw[(cl + 16*ri) * OH_STR +      kg*8];
        ao[w][1] = *(const short8*)&ohw[(cl + 16*ri) * OH_STR + 32 + kg*8];
      }
      #pragma unroll
      for (int j = 0; j < 6; ++j) {
        int ct = cg*6 + j;
        short8 bw0 = loadW<WBF>(outw, ct, 48, pr*8,     l, ct*16 + cl, 384, pr*64      + kg*8);
        short8 bw1 = loadW<WBF>(outw, ct, 48, pr*8 + 4, l, ct*16 + cl, 384, pr*64 + 32 + kg*8);
        opacc[0][j] = MFMA_B16(ao[0][0], bw0, opacc[0][j]);
        opacc[0][j] = MFMA_B16(ao[0][1], bw1, opacc[0][j]);
        opacc[1][j] = MFMA_B16(ao[1][0], bw0, opacc[1][j]);
        opacc[1][j] = MFMA_B16(ao[1][1], bw1, opacc[1][j]);
      }
      if (pr < 5) qkv(pr + 1);
    }
    __syncthreads();
  }

  #pragma unroll
  for (int w = 0; w < 2; ++w)
    #pragma unroll
    for (int j = 0; j < 6; ++j) {
      int col = (cg*6 + j) * 16 + cl;
      float ob = outb[col];
      #pragma unroll
      for (int rg = 0; rg < 4; ++rg) {
        int row = 16*ri + kg*4 + rg;
        if (row < 49) {
          size_t g = gidxw(w, row, col);
          out[g] = tokens[g] + opacc[w][j][rg] + ob;
        }
      }
    }
  __syncthreads();

  ln_pass(out, ln2g, ln2b);
  __syncthreads();

  f32x4 macc[2][2][3];
  #pragma unroll
  for (int a = 0; a < 2; ++a)
    #pragma unroll
    for (int t = 0; t < 2; ++t)
      #pragma unroll
      for (int j = 0; j < 3; ++j) macc[a][t][j] = f32x4{0.f,0.f,0.f,0.f};

  const int rp = gw & 1, cg3 = gw >> 1;

  auto mlp1 = [&](int cc, int pb) {
    f32x4 e00{0,0,0,0}, e01{0,0,0,0}, e10{0,0,0,0}, e11{0,0,0,0};
    #pragma unroll
    for (int kt = 0; kt < 12; ++kt) {
      int k0 = kt * 32 + kg * 8;
      short8 wb0 = loadW<WBF>(w1, cc*8 + cg*2 + 0, 48, kt*4, l, (cc*8+cg*2+0)*16 + cl, 384, k0);
      short8 wb1 = loadW<WBF>(w1, cc*8 + cg*2 + 1, 48, kt*4, l, (cc*8+cg*2+1)*16 + cl, 384, k0);
      short8 a0 = *(const short8*)&alnW[0][arowA + k0];
      short8 a1 = *(const short8*)&alnW[1][arowA + k0];
      e00 = MFMA_B16(a0, wb0, e00); e01 = MFMA_B16(a0, wb1, e01);
      e10 = MFMA_B16(a1, wb0, e10); e11 = MFMA_B16(a1, wb1, e11);
    }
    #pragma unroll
    for (int w = 0; w < 2; ++w) {
      unsigned short* hb = (unsigned short*)(poolW[w] + pb * HIDB);
      #pragma unroll
      for (int j = 0; j < 2; ++j) {
        f32x4 ee = (w == 0) ? (j == 0 ? e00 : e01) : (j == 0 ? e10 : e11);
        int n = cc*128 + (cg*2 + j)*16 + cl;
        float bb = b1[n];
        #pragma unroll
        for (int rg = 0; rg < 4; ++rg) {
          int row = 16*ri + kg*4 + rg;
          if (row < 49) {
            float x = ee[rg] + bb;
            float t2 = 0.044715f * x * x;
            float arg = __builtin_fmaf(t2, x, x);
            float e = __expf(1.5957691216f * arg);
            float gl = x * (e / (e + 1.f));
            hb[row * HID_STR + (cg*2 + j)*16 + cl] = f2bfu(gl);
          }
        }
      }
    }
  };
  auto mlp2 = [&](int cc, int pb) {
    unsigned short* hb0 = (unsigned short*)(poolW[0] + pb * HIDB);
    unsigned short* hb1 = (unsigned short*)(poolW[1] + pb * HIDB);
    #pragma unroll
    for (int kt = 0; kt < 4; ++kt) {
      int k0 = kt * 32 + kg * 8;
      short8 hd00 = *(const short8*)&hb0[(cl + 16*(2*rp    )) * HID_STR + k0];
      short8 hd01 = *(const short8*)&hb0[(cl + 16*(2*rp + 1)) * HID_STR + k0];
      short8 hd10 = *(const short8*)&hb1[(cl + 16*(2*rp    )) * HID_STR + k0];
      short8 hd11 = *(const short8*)&hb1[(cl + 16*(2*rp + 1)) * HID_STR + k0];
      #pragma unroll
      for (int j = 0; j < 3; ++j) {
        int ct = cg3*3 + j;
        short8 bw = loadW<WBF>(w2, ct, 192, cc*16 + kt*4, l,
                               ct*16 + cl, 1536, cc*128 + k0);
        macc[0][0][j] = MFMA_B16(hd00, bw, macc[0][0][j]);
        macc[0][1][j] = MFMA_B16(hd01, bw, macc[0][1][j]);
        macc[1][0][j] = MFMA_B16(hd10, bw, macc[1][0][j]);
        macc[1][1][j] = MFMA_B16(hd11, bw, macc[1][1][j]);
      }
    }
  };

  mlp1(0, 0);
  __syncthreads();
  for (int cc = 1; cc < 12; ++cc) {
    mlp2(cc - 1, (cc - 1) & 1);
    mlp1(cc, cc & 1);
    __syncthreads();
  }
  mlp2(11, 1);

  #pragma unroll
  for (int w = 0; w < 2; ++w)
    #pragma unroll
    for (int t = 0; t < 2; ++t)
      #pragma unroll
      for (int j = 0; j < 3; ++j) {
        int col = (cg3*3 + j) * 16 + cl;
        float bb2 = b2[col];
        #pragma unroll
        for (int rg = 0; rg < 4; ++rg) {
          int row = 16*(2*rp + t) + kg*4 + rg;
          if (row < 49) {
            size_t g = gidxw(w, row, col);
            out[g] = out[g] + macc[w][t][j][rg] + bb2;
          }
        }
      }
}

// ws layout: [aln/oh 19267584][qkv/aln2 57802752][packed weights 1769472] bf16 elems
#define OFF_ALN  0ull
#define OFF_QKV  19267584ull
#define OFF_WP   77070336ull
#define WS_IPW   0
#define WS_OUTW  442368
#define WS_W1    589824
#define WS_W2    1179648
#define WS_TOT   1769472
#define WS_NEED  ((OFF_WP + (unsigned long long)WS_TOT) * 2ull)

extern "C" void kernel_launch(void* const* d_in, const int* in_sizes, int n_in,
                              void* d_out, int out_size, void* d_ws, size_t ws_size,
                              hipStream_t stream) {
  (void)in_sizes; (void)n_in; (void)out_size;
  const float* tokens = (const float*)d_in[0];
  const float* ipw  = (const float*)d_in[1];
  const float* ipb  = (const float*)d_in[2];
  const float* outw = (const float*)d_in[3];
  const float* outb = (const float*)d_in[4];
  const float* ln1g = (const float*)d_in[5];
  const float* ln1b = (const float*)d_in[6];
  const float* w1   = (const float*)d_in[7];
  const float* b1   = (const float*)d_in[8];
  const float* w2   = (const float*)d_in[9];
  const float* b2   = (const float*)d_in[10];
  const float* ln2g = (const float*)d_in[11];
  const float* ln2b = (const float*)d_in[12];
  float* out = (float*)d_out;
  unsigned short* wsp = (unsigned short*)d_ws;

  if (ws_size >= (size_t)WS_NEED) {
    unsigned short* wp = wsp + OFF_WP;
    hipLaunchKernelGGL(cvt_pack, dim3((442368+511)/512), dim3(512), 0, stream, ipw,  wp + WS_IPW,  384,  442368);
    hipLaunchKernelGGL(cvt_pack, dim3((147456+511)/512), dim3(512), 0, stream, outw, wp + WS_OUTW, 384,  147456);
    hipLaunchKernelGGL(cvt_pack, dim3((589824+511)/512), dim3(512), 0, stream, w1,   wp + WS_W1,   384,  589824);
    hipLaunchKernelGGL(cvt_pack, dim3((589824+511)/512), dim3(512), 0, stream, w2,   wp + WS_W2,   1536, 589824);
    (void)hipFuncSetAttribute((const void*)mlp_fused,
                              hipFuncAttributeMaxDynamicSharedMemorySize, 66560);
    hipLaunchKernelGGL(ln1_k, dim3(784), dim3(512), 0, stream,
                       tokens, ln1g, ln1b, wsp + OFF_ALN);
    hipLaunchKernelGGL(qkv_gemm, dim3(784, 3), dim3(512), 49152, stream,
                       wsp + OFF_ALN, wp + WS_IPW, ipb, wsp + OFF_QKV);
    hipLaunchKernelGGL(attn_k, dim3(1024), dim3(256), 0, stream,
                       wsp + OFF_QKV, wsp + OFF_ALN);
    hipLaunchKernelGGL(outproj_k, dim3(784), dim3(512), 49152, stream,
                       wsp + OFF_ALN, wp + WS_OUTW, outb, tokens, ln2g, ln2b,
                       out, wsp + OFF_QKV);
    hipLaunchKernelGGL(mlp_fused, dim3(784), dim3(512), 66560, stream,
                       wsp + OFF_QKV, wp + WS_W1, b1, wp + WS_W2, b2, out);
  } else if (ws_size >= (size_t)WS_TOT * 2) {
    hipLaunchKernelGGL(cvt_pack, dim3((442368+511)/512), dim3(512), 0, stream, ipw,  wsp + WS_IPW,  384,  442368);
    hipLaunchKernelGGL(cvt_pack, dim3((147456+511)/512), dim3(512), 0, stream, outw, wsp + WS_OUTW, 384,  147456);
    hipLaunchKernelGGL(cvt_pack, dim3((589824+511)/512), dim3(512), 0, stream, w1,   wsp + WS_W1,   384,  589824);
    hipLaunchKernelGGL(cvt_pack, dim3((589824+511)/512), dim3(512), 0, stream, w2,   wsp + WS_W2,   1536, 589824);
    (void)hipFuncSetAttribute((const void*)swin_mfma<true>,
                              hipFuncAttributeMaxDynamicSharedMemorySize, SMEM_BYTES);
    hipLaunchKernelGGL((swin_mfma<true>), dim3(512), dim3(1024), SMEM_BYTES, stream,
                       tokens, (const void*)(wsp + WS_IPW), ipb,
                       (const void*)(wsp + WS_OUTW), outb, ln1g, ln1b,
                       (const void*)(wsp + WS_W1), b1, (const void*)(wsp + WS_W2), b2,
                       ln2g, ln2b, out);
  } else {
    (void)hipFuncSetAttribute((const void*)swin_mfma<false>,
                              hipFuncAttributeMaxDynamicSharedMemorySize, SMEM_BYTES);
    hipLaunchKernelGGL((swin_mfma<false>), dim3(512), dim3(1024), SMEM_BYTES, stream,
                       tokens, (const void*)ipw, ipb, (const void*)outw, outb, ln1g, ln1b,
                       (const void*)w1, b1, (const void*)w2, b2, ln2g, ln2b, out);
  }
}

// Round 10
// 810.224 us; speedup vs baseline: 1.4705x; 1.4705x over previous
//
#include <hip/hip_runtime.h>
#include <hip/hip_bf16.h>
#include <math.h>

using short8 = __attribute__((ext_vector_type(8))) short;
using f32x4  = __attribute__((ext_vector_type(4))) float;
using f32x16 = __attribute__((ext_vector_type(16))) float;

#define MFMA16(A,B,C) __builtin_amdgcn_mfma_f32_16x16x32_bf16((A),(B),(C),0,0,0)
#define MFMA32(A,B,C) __builtin_amdgcn_mfma_f32_32x32x16_bf16((A),(B),(C),0,0,0)

// ---------------- LDS layout (bytes) ----------------
// aln [49][388]u16 row-major (rows 49..63 spill into pool: garbage feeds only
// discarded/masked outputs). Pool: q2/k2 [49][66], vT2 [64][66] (zero-init,
// token cols>=49 stay 0), oh [49][66] (+spill for 32x32 reads). MLP: hidF in
// 32-col fragment order [rt2][kc8][lane64][e8] aliases pool.
#define ALN_STR 388
#define Q2_OFF  38024
#define K2_OFF  44492
#define VT_OFF  50960
#define OH_OFF  59408
#define HID_OFF 38024
#define ASTR    66
#define SMEM_BYTES 68608

__device__ __forceinline__ unsigned short f2bfu(float x) {   // RNE f32->bf16
  unsigned u = __float_as_uint(x);
  return (unsigned short)((u + 0x7fffu + ((u >> 16) & 1u)) >> 16);
}
__device__ __forceinline__ unsigned pk2(float a, float b) {
  return (unsigned)f2bfu(a) | ((unsigned)f2bfu(b) << 16);
}

// pack f32 [N][K] -> 32-col fragment order [ct][kc16][lane64][e8] bf16
__global__ void cvt_pack32(const float* __restrict__ src, unsigned short* __restrict__ dst,
                           int K, int n) {
  int K16 = K >> 4;
  int i = blockIdx.x * blockDim.x + threadIdx.x;
  if (i >= n) return;
  int e = i & 7;
  int l = (i >> 3) & 63;
  int idx = i >> 9;
  int kc = idx % K16, ct = idx / K16;
  dst[i] = f2bfu(src[(size_t)(ct * 32 + (l & 31)) * K + kc * 16 + (l >> 5) * 8 + e]);
}

// B fragment load (32x32): lane l -> col=l&31, k=kc*16+(l>>5)*8+e
template<bool WBF>
__device__ __forceinline__ short8 ldw32(const void* wp, int tile, int K16, int kc,
                                        int l, int K) {
  if constexpr (WBF) {
    return *(const short8*)((const unsigned short*)wp +
                            (((size_t)(tile * K16 + kc)) << 9) + l * 8);
  } else {
    const float* p = (const float*)wp + (size_t)(tile * 32 + (l & 31)) * K + kc * 16 + (l >> 5) * 8;
    float4 x = *(const float4*)p;
    float4 y = *(const float4*)(p + 4);
    short8 r;
    r[0]=(short)f2bfu(x.x); r[1]=(short)f2bfu(x.y); r[2]=(short)f2bfu(x.z); r[3]=(short)f2bfu(x.w);
    r[4]=(short)f2bfu(y.x); r[5]=(short)f2bfu(y.y); r[6]=(short)f2bfu(y.z); r[7]=(short)f2bfu(y.w);
    return r;
  }
}

template<bool WBF>
__global__ __launch_bounds__(512, 4)
void swin32(const float* __restrict__ tokens,
            const void* __restrict__ ipw,  const float* __restrict__ ipb,
            const void* __restrict__ outw, const float* __restrict__ outb,
            const float* __restrict__ ln1g, const float* __restrict__ ln1b,
            const void* __restrict__ w1,   const float* __restrict__ b1,
            const void* __restrict__ w2,   const float* __restrict__ b2,
            const float* __restrict__ ln2g, const float* __restrict__ ln2b,
            float* __restrict__ out)
{
  extern __shared__ char smem[];
  unsigned short* aln  = (unsigned short*)smem;
  unsigned short* q2   = (unsigned short*)(smem + Q2_OFF);
  unsigned short* k2   = (unsigned short*)(smem + K2_OFF);
  unsigned short* vT2  = (unsigned short*)(smem + VT_OFF);
  unsigned short* oh   = (unsigned short*)(smem + OH_OFF);
  unsigned short* hidF = (unsigned short*)(smem + HID_OFF);

  const int tid = threadIdx.x;
  const int l = tid & 63, wv = tid >> 6;
  const int cl = l & 15, kg = l >> 4;       // 16x16 decomp (attention)
  const int l31 = l & 31, h2 = l >> 5;      // 32x32 decomp
  const int crow0 = 4 * h2;
  const int wid = blockIdx.x;
  const int iw = wid & 7, ih = (wid >> 3) & 7, bt = wid >> 6;

  auto gidx = [&](int r, int c) -> size_t {
    int wi = r / 7, wj = r - wi * 7;
    return ((size_t)bt * 3136 + (size_t)((ih*7 + wi) * 56 + iw*7 + wj)) * 384 + c;
  };

  auto ln_pass = [&](const float* src, const float* gw, const float* gb) {
    int row = tid >> 3, lj = tid & 7;
    if (row < 49) {
      size_t base = gidx(row, 0);
      float4 xv[12];
      float sx = 0.f, sxx = 0.f;
      #pragma unroll
      for (int k = 0; k < 12; ++k) {
        xv[k] = *(const float4*)&src[base + (lj + 8*k) * 4];
        sx  += xv[k].x + xv[k].y + xv[k].z + xv[k].w;
        sxx += xv[k].x*xv[k].x + xv[k].y*xv[k].y + xv[k].z*xv[k].z + xv[k].w*xv[k].w;
      }
      #pragma unroll
      for (int d = 1; d < 8; d <<= 1) { sx += __shfl_xor(sx, d, 8); sxx += __shfl_xor(sxx, d, 8); }
      float mean = sx * (1.f/384.f);
      float rs = rsqrtf(sxx * (1.f/384.f) - mean*mean + 1e-5f);
      unsigned short* arow = aln + row * ALN_STR;
      #pragma unroll
      for (int k = 0; k < 12; ++k) {
        int c = (lj + 8*k) * 4;
        float4 gv = *(const float4*)&gw[c];
        float4 bv = *(const float4*)&gb[c];
        unsigned u0 = pk2((xv[k].x-mean)*rs*gv.x + bv.x, (xv[k].y-mean)*rs*gv.y + bv.y);
        unsigned u1 = pk2((xv[k].z-mean)*rs*gv.z + bv.z, (xv[k].w-mean)*rs*gv.w + bv.w);
        *(uint2*)&arow[c] = make_uint2(u0, u1);
      }
    }
  };

  // A-read (32x32) from row-major aln: row = rt*32+l31, k = kc*16 + h2*8
  auto ldA = [&](int rt, int kc) -> short8 {
    return *(const short8*)&aln[(rt*32 + l31) * ALN_STR + kc*16 + h2*8];
  };

  // QKV (32x32) for head pair pr: 12 tile-tasks (6 ct x 2 rt) over 8 waves.
  auto qkv32 = [&](int pr) {
    #pragma unroll
    for (int rnd = 0; rnd < 2; ++rnd) {
      int t = rnd * 8 + wv;
      if (t < 12) {
        int ct6 = t % 6, rt = t / 6;
        int part = ct6 >> 1, hp = ct6 & 1, hh = 2*pr + hp;
        int wtile = part * 12 + hh;
        f32x16 acc = {};
        for (int kc = 0; kc < 24; ++kc) {
          short8 a = ldA(rt, kc);
          short8 b = ldw32<WBF>(ipw, wtile, 24, kc, l, 384);
          acc = MFMA32(a, b, acc);
        }
        float bias = ipb[part * 384 + hh * 32 + l31];
        float scl = (part == 0) ? 0.17677669529663687f : 1.f;
        #pragma unroll
        for (int r = 0; r < 16; ++r) {
          int row = rt*32 + (r & 3) + 8*(r >> 2) + crow0;
          if (row < 49) {
            unsigned short v = f2bfu((acc[r] + bias) * scl);
            if      (part == 0) q2[row * ASTR + hp*32 + l31] = v;
            else if (part == 1) k2[row * ASTR + hp*32 + l31] = v;
            else                vT2[(hp*32 + l31) * ASTR + row] = v;
          }
        }
      }
    }
  };

  // ---- init: zero vT2 (token cols >=49 must stay 0), LN1 ----
  for (int i = tid; i < 8448/4; i += 512) ((unsigned*)(smem + VT_OFF))[i] = 0u;
  ln_pass(tokens, ln1g, ln1b);
  __syncthreads();

  const int rt = wv & 1, cq = wv >> 1;      // 32x32 GEMM wave role
  f32x16 opacc[3];
  #pragma unroll
  for (int j = 0; j < 3; ++j) opacc[j] = f32x16{};

  qkv32(0);
  __syncthreads();

  const int hl = wv & 1, qci = wv >> 1;     // attention wave role

  for (int pr = 0; pr < 6; ++pr) {
    // ---- P_a: scores (swapped mfma(K,Q)) + in-register softmax + PV (16x16) ----
    {
      short8 bq = *(const short8*)&q2[(16*qci + cl) * ASTR + hl*32 + kg*8];
      f32x4 dsc[4];
      #pragma unroll
      for (int kri = 0; kri < 4; ++kri) {
        short8 ak = *(const short8*)&k2[(16*kri + cl) * ASTR + hl*32 + kg*8];
        f32x4 z{0.f,0.f,0.f,0.f};
        dsc[kri] = MFMA16(ak, bq, z);
      }
      float ev[4][4];
      float mx = -1e30f;
      #pragma unroll
      for (int kri = 0; kri < 4; ++kri)
        #pragma unroll
        for (int r = 0; r < 4; ++r) {
          int kidx = 16*kri + 4*kg + r;
          float v = (kidx < 49) ? dsc[kri][r] : -1e30f;
          ev[kri][r] = v;
          mx = fmaxf(mx, v);
        }
      mx = fmaxf(mx, __shfl_xor(mx, 16));
      mx = fmaxf(mx, __shfl_xor(mx, 32));
      float sum = 0.f;
      #pragma unroll
      for (int kri = 0; kri < 4; ++kri)
        #pragma unroll
        for (int r = 0; r < 4; ++r) {
          float e = __expf(ev[kri][r] - mx);
          ev[kri][r] = e; sum += e;
        }
      sum += __shfl_xor(sum, 16);
      sum += __shfl_xor(sum, 32);
      float inv = 1.f / sum;
      unsigned pk[4][2];
      #pragma unroll
      for (int kri = 0; kri < 4; ++kri) {
        pk[kri][0] = pk2(ev[kri][0]*inv, ev[kri][1]*inv);
        pk[kri][1] = pk2(ev[kri][2]*inv, ev[kri][3]*inv);
      }
      f32x4 dot0{0.f,0.f,0.f,0.f}, dot1{0.f,0.f,0.f,0.f};
      const int sA = cl + 32 * (kg & 1);
      const bool hi = (kg >> 1) & 1;
      #pragma unroll
      for (int kt = 0; kt < 2; ++kt) {
        unsigned x0 = (unsigned)__shfl((int)pk[2*kt][0],   sA);
        unsigned x1 = (unsigned)__shfl((int)pk[2*kt][1],   sA);
        unsigned x2 = (unsigned)__shfl((int)pk[2*kt][0],   sA + 16);
        unsigned x3 = (unsigned)__shfl((int)pk[2*kt][1],   sA + 16);
        unsigned y0 = (unsigned)__shfl((int)pk[2*kt+1][0], sA);
        unsigned y1 = (unsigned)__shfl((int)pk[2*kt+1][1], sA);
        unsigned y2 = (unsigned)__shfl((int)pk[2*kt+1][0], sA + 16);
        unsigned y3 = (unsigned)__shfl((int)pk[2*kt+1][1], sA + 16);
        uint4 bu = make_uint4(hi ? y0 : x0, hi ? y1 : x1, hi ? y2 : x2, hi ? y3 : x3);
        short8 bfrag = *(short8*)&bu;
        short8 a0 = *(const short8*)&vT2[(hl*32 +  0 + cl) * ASTR + kt*32 + kg*8];
        short8 a1 = *(const short8*)&vT2[(hl*32 + 16 + cl) * ASTR + kt*32 + kg*8];
        dot0 = MFMA16(a0, bfrag, dot0);
        dot1 = MFMA16(a1, bfrag, dot1);
      }
      int q = 16*qci + cl;
      if (q < 49) {
        int base = q * ASTR + hl*32 + kg*4;
        *(unsigned*)&oh[base     ] = pk2(dot0[0], dot0[1]);
        *(unsigned*)&oh[base +  2] = pk2(dot0[2], dot0[3]);
        *(unsigned*)&oh[base + 16] = pk2(dot1[0], dot1[1]);
        *(unsigned*)&oh[base + 18] = pk2(dot1[2], dot1[3]);
      }
    }
    __syncthreads();

    // ---- P_b: out-proj(pr) 32x32 (K=64) + QKV(pr+1) ----
    {
      short8 aoh[4];
      #pragma unroll
      for (int kc2 = 0; kc2 < 4; ++kc2)
        aoh[kc2] = *(const short8*)&oh[(rt*32 + l31) * ASTR + kc2*16 + h2*8];
      #pragma unroll
      for (int j = 0; j < 3; ++j) {
        #pragma unroll
        for (int kc2 = 0; kc2 < 4; ++kc2) {
          short8 b = ldw32<WBF>(outw, cq*3 + j, 24, pr*4 + kc2, l, 384);
          opacc[j] = MFMA32(aoh[kc2], b, opacc[j]);
        }
      }
      if (pr < 5) qkv32(pr + 1);
    }
    __syncthreads();
  }

  // ---- win = tokens + attn + out_b -> out ----
  #pragma unroll
  for (int j = 0; j < 3; ++j) {
    int col = (cq*3 + j) * 32 + l31;
    float ob = outb[col];
    #pragma unroll
    for (int r = 0; r < 16; ++r) {
      int row = rt*32 + (r & 3) + 8*(r >> 2) + crow0;
      if (row < 49) {
        size_t g = gidx(row, col);
        out[g] = tokens[g] + opacc[j][r] + ob;
      }
    }
  }
  __syncthreads();

  // ---- LN2 ----
  ln_pass(out, ln2g, ln2b);
  __syncthreads();

  // ---- MLP (32x32): hidF in fragment order, MLP2 accumulated in regs ----
  f32x16 macc[3];
  #pragma unroll
  for (int j = 0; j < 3; ++j) macc[j] = f32x16{};

  for (int cc = 0; cc < 12; ++cc) {
    {   // MLP1: wave (rt, ctl=cq): tile cc*4+cq, all 64 rows (garbage rows ok)
      f32x16 e = {};
      for (int kc = 0; kc < 24; ++kc) {
        short8 a = ldA(rt, kc);
        short8 b = ldw32<WBF>(w1, cc*4 + cq, 24, kc, l, 384);
        e = MFMA32(a, b, e);
      }
      float bb = b1[cc*128 + cq*32 + l31];
      int hcol = cq*32 + l31;
      int kcH = hcol >> 4, hH = (hcol >> 3) & 1, eH = hcol & 7;
      #pragma unroll
      for (int r = 0; r < 16; ++r) {
        int row = rt*32 + (r & 3) + 8*(r >> 2) + crow0;
        float x = e[r] + bb;
        // gelu(x) ~= x * sigmoid(1.5957691(x + 0.044715 x^3))
        float t2 = 0.044715f * x * x;
        float arg = __builtin_fmaf(t2, x, x);
        float ex = __expf(1.5957691216f * arg);
        hidF[rt*4096 + kcH*512 + ((hH << 5) | (row & 31)) * 8 + eH] =
            f2bfu(x * (ex / (ex + 1.f)));
      }
    }
    __syncthreads();
    {   // MLP2: wave (rt, cq): 3 ct, K=128 (8 kc), conflict-free A reads
      #pragma unroll
      for (int kc = 0; kc < 8; ++kc) {
        short8 ha = *(const short8*)&hidF[rt*4096 + kc*512 + l*8];
        #pragma unroll
        for (int j = 0; j < 3; ++j) {
          short8 b = ldw32<WBF>(w2, cq*3 + j, 96, cc*8 + kc, l, 1536);
          macc[j] = MFMA32(ha, b, macc[j]);
        }
      }
    }
    __syncthreads();
  }

  // ---- final: out += mlp + b2 ----
  #pragma unroll
  for (int j = 0; j < 3; ++j) {
    int col = (cq*3 + j) * 32 + l31;
    float bb2 = b2[col];
    #pragma unroll
    for (int r = 0; r < 16; ++r) {
      int row = rt*32 + (r & 3) + 8*(r >> 2) + crow0;
      if (row < 49) {
        size_t g = gidx(row, col);
        out[g] = out[g] + macc[j][r] + bb2;
      }
    }
  }
}

// ws layout (bf16 elements): ipw[442368] | outw[147456] | w1[589824] | w2[589824]
#define WS_IPW  0
#define WS_OUTW 442368
#define WS_W1   589824
#define WS_W2   1179648
#define WS_TOT  1769472

extern "C" void kernel_launch(void* const* d_in, const int* in_sizes, int n_in,
                              void* d_out, int out_size, void* d_ws, size_t ws_size,
                              hipStream_t stream) {
  (void)in_sizes; (void)n_in; (void)out_size;
  const float* tokens = (const float*)d_in[0];
  const float* ipw  = (const float*)d_in[1];
  const float* ipb  = (const float*)d_in[2];
  const float* outw = (const float*)d_in[3];
  const float* outb = (const float*)d_in[4];
  const float* ln1g = (const float*)d_in[5];
  const float* ln1b = (const float*)d_in[6];
  const float* w1   = (const float*)d_in[7];
  const float* b1   = (const float*)d_in[8];
  const float* w2   = (const float*)d_in[9];
  const float* b2   = (const float*)d_in[10];
  const float* ln2g = (const float*)d_in[11];
  const float* ln2b = (const float*)d_in[12];
  float* out = (float*)d_out;

  bool wbf = (ws_size >= (size_t)WS_TOT * 2);
  if (wbf) {
    unsigned short* wsp = (unsigned short*)d_ws;
    hipLaunchKernelGGL(cvt_pack32, dim3((442368+511)/512), dim3(512), 0, stream, ipw,  wsp + WS_IPW,  384,  442368);
    hipLaunchKernelGGL(cvt_pack32, dim3((147456+511)/512), dim3(512), 0, stream, outw, wsp + WS_OUTW, 384,  147456);
    hipLaunchKernelGGL(cvt_pack32, dim3((589824+511)/512), dim3(512), 0, stream, w1,   wsp + WS_W1,   384,  589824);
    hipLaunchKernelGGL(cvt_pack32, dim3((589824+511)/512), dim3(512), 0, stream, w2,   wsp + WS_W2,   1536, 589824);
    (void)hipFuncSetAttribute((const void*)swin32<true>,
                              hipFuncAttributeMaxDynamicSharedMemorySize, SMEM_BYTES);
    hipLaunchKernelGGL((swin32<true>), dim3(1024), dim3(512), SMEM_BYTES, stream,
                       tokens, (const void*)(wsp + WS_IPW), ipb,
                       (const void*)(wsp + WS_OUTW), outb, ln1g, ln1b,
                       (const void*)(wsp + WS_W1), b1, (const void*)(wsp + WS_W2), b2,
                       ln2g, ln2b, out);
  } else {
    (void)hipFuncSetAttribute((const void*)swin32<false>,
                              hipFuncAttributeMaxDynamicSharedMemorySize, SMEM_BYTES);
    hipLaunchKernelGGL((swin32<false>), dim3(1024), dim3(512), SMEM_BYTES, stream,
                       tokens, (const void*)ipw, ipb, (const void*)outw, outb, ln1g, ln1b,
                       (const void*)w1, b1, (const void*)w2, b2, ln2g, ln2b, out);
  }
}

// Round 11
// 505.023 us; speedup vs baseline: 2.3592x; 1.6043x over previous
//
#include <hip/hip_runtime.h>
#include <hip/hip_bf16.h>
#include <math.h>

using short8 = __attribute__((ext_vector_type(8))) short;
using f32x4  = __attribute__((ext_vector_type(4))) float;

#define MFMA_B16(A,B,C) __builtin_amdgcn_mfma_f32_16x16x32_bf16((A),(B),(C),0,0,0)

// ---------------- LDS layout (bytes) ----------------
// aln [49][392]u16; q2/k2 [49][72]u16 (rows>=49 garbage: masked or discarded);
// vT2 [64][72]u16 (token cols>=49 zero-init, never overwritten); oh [64][72]u16
// (rows>=49 garbage -> discarded C rows). MLP: hid double-buffer [64][136]u16
// aliases q2..oh pool. Total 79 KiB -> 2 blocks/CU.
#define ALN_STR 392
#define Q2_OFF  38416
#define QK_STR  72
#define K2_OFF  45472
#define VT_OFF  52528
#define VT_STR  72
#define OH_OFF  61744
#define OH_STR  72
#define HID0_OFF 38416
#define HID1_OFF 55824
#define HID_STR 136
#define SMEM_BYTES 80896   // 79 KiB

__device__ __forceinline__ unsigned short f2bfu(float x) {   // RNE f32->bf16
  unsigned u = __float_as_uint(x);
  return (unsigned short)((u + 0x7fffu + ((u >> 16) & 1u)) >> 16);
}
__device__ __forceinline__ unsigned pk2(float a, float b) {
  return (unsigned)f2bfu(a) | ((unsigned)f2bfu(b) << 16);
}

// B-operand load. WBF: packed fragment layout [tile][kchunk][lane][8] bf16 ->
// one coalesced 16B/lane read. !WBF: gather from f32 row-major + convert.
template<bool WBF>
__device__ __forceinline__ short8 loadW(const void* base, int tile, int K8, int kcb,
                                        int l, int row, int ldk, int k0) {
  if constexpr (WBF) {
    return *(const short8*)((const unsigned short*)base +
                            (((size_t)(tile * K8 + kcb)) << 7) + l * 8);
  } else {
    const float* p = (const float*)base + (size_t)row * ldk + k0;
    float4 x = *(const float4*)p;
    float4 y = *(const float4*)(p + 4);
    short8 r;
    r[0]=(short)f2bfu(x.x); r[1]=(short)f2bfu(x.y); r[2]=(short)f2bfu(x.z); r[3]=(short)f2bfu(x.w);
    r[4]=(short)f2bfu(y.x); r[5]=(short)f2bfu(y.y); r[6]=(short)f2bfu(y.z); r[7]=(short)f2bfu(y.w);
    return r;
  }
}

// Repack f32 [rows][K] -> bf16 fragment order [tile][kc][r16][8].
__global__ void cvt_pack(const float* __restrict__ src, unsigned short* __restrict__ dst,
                         int K, int n) {
  int K8 = K >> 3;
  int i = blockIdx.x * blockDim.x + threadIdx.x;
  if (i >= n) return;
  int e = i & 7;
  int idx = i >> 3;
  int r = idx & 15; idx >>= 4;
  int kc = idx % K8, ci = idx / K8;
  dst[i] = f2bfu(src[(size_t)(ci * 16 + r) * K + kc * 8 + e]);
}

template<bool WBF>
__global__ __launch_bounds__(512, 4)
void swin_mfma(const float* __restrict__ tokens,
               const void* __restrict__ ipw,  const float* __restrict__ ipb,
               const void* __restrict__ outw, const float* __restrict__ outb,
               const float* __restrict__ ln1g, const float* __restrict__ ln1b,
               const void* __restrict__ w1,   const float* __restrict__ b1,
               const void* __restrict__ w2,   const float* __restrict__ b2,
               const float* __restrict__ ln2g, const float* __restrict__ ln2b,
               float* __restrict__ out)
{
  extern __shared__ char smem[];
  unsigned short* aln  = (unsigned short*)smem;
  unsigned short* q2   = (unsigned short*)(smem + Q2_OFF);
  unsigned short* k2   = (unsigned short*)(smem + K2_OFF);
  unsigned short* vT2  = (unsigned short*)(smem + VT_OFF);
  unsigned short* oh   = (unsigned short*)(smem + OH_OFF);
  unsigned short* hid0 = (unsigned short*)(smem + HID0_OFF);
  unsigned short* hid1 = (unsigned short*)(smem + HID1_OFF);

  const int tid = threadIdx.x;
  const int l  = tid & 63, wv = tid >> 6;
  const int cl = l & 15,  kg = l >> 4;
  const int wid = blockIdx.x;
  const int iw = wid & 7, ih = (wid >> 3) & 7, bt = wid >> 6;

  auto gidx = [&](int r, int c) -> size_t {
    int wi = r / 7, wj = r - wi * 7;
    return ((size_t)bt * 3136 + (size_t)((ih*7 + wi) * 56 + iw*7 + wj)) * 384 + c;
  };

  auto ln_pass = [&](const float* src, const float* gw, const float* gb) {
    int grp = tid >> 3, lj = tid & 7;
    if (grp < 49) {
      size_t base = gidx(grp, 0);
      float4 xv[12];
      float sx = 0.f, sxx = 0.f;
      #pragma unroll
      for (int k = 0; k < 12; ++k) {
        xv[k] = *(const float4*)&src[base + (lj + 8*k) * 4];
        sx  += xv[k].x + xv[k].y + xv[k].z + xv[k].w;
        sxx += xv[k].x*xv[k].x + xv[k].y*xv[k].y + xv[k].z*xv[k].z + xv[k].w*xv[k].w;
      }
      #pragma unroll
      for (int d = 1; d < 8; d <<= 1) { sx += __shfl_xor(sx, d, 8); sxx += __shfl_xor(sxx, d, 8); }
      float mean = sx * (1.f/384.f);
      float rs = rsqrtf(sxx * (1.f/384.f) - mean*mean + 1e-5f);
      unsigned short* arow = aln + grp * ALN_STR;
      #pragma unroll
      for (int k = 0; k < 12; ++k) {
        int c = (lj + 8*k) * 4;
        float4 gv = *(const float4*)&gw[c];
        float4 bv = *(const float4*)&gb[c];
        unsigned u0 = pk2((xv[k].x-mean)*rs*gv.x + bv.x, (xv[k].y-mean)*rs*gv.y + bv.y);
        unsigned u1 = pk2((xv[k].z-mean)*rs*gv.z + bv.z, (xv[k].w-mean)*rs*gv.w + bv.w);
        *(uint2*)&arow[c] = make_uint2(u0, u1);
      }
    }
  };

  const int ri0 = wv & 3, chalf = wv >> 2;
  const int arow0 = (cl + 16 * ri0) * ALN_STR;

  // QKV for head pair pr: writes q2/k2/vT2 (rows<49 only).
  auto qkv = [&](int pr) {
    #pragma unroll
    for (int half = 0; half < 2; ++half) {
      int cia[3], tilea[3], growa[3];
      #pragma unroll
      for (int j = 0; j < 3; ++j) {
        int ci = chalf + 2 * (half * 3 + j);
        int part = ci >> 2, wt = ci & 3;
        cia[j] = ci;
        tilea[j] = part * 24 + pr * 4 + wt;
        growa[j] = part * 384 + pr * 64 + wt * 16 + cl;
      }
      f32x4 d0{0,0,0,0}, d1{0,0,0,0}, d2{0,0,0,0};
      __builtin_amdgcn_s_setprio(1);
      #pragma unroll
      for (int kt = 0; kt < 12; ++kt) {
        int k0 = kt * 32 + kg * 8;
        short8 a = *(const short8*)&aln[arow0 + k0];
        short8 b0 = loadW<WBF>(ipw, tilea[0], 48, kt*4, l, growa[0], 384, k0);
        short8 b1 = loadW<WBF>(ipw, tilea[1], 48, kt*4, l, growa[1], 384, k0);
        short8 b2 = loadW<WBF>(ipw, tilea[2], 48, kt*4, l, growa[2], 384, k0);
        d0 = MFMA_B16(a, b0, d0);
        d1 = MFMA_B16(a, b1, d1);
        d2 = MFMA_B16(a, b2, d2);
      }
      __builtin_amdgcn_s_setprio(0);
      #pragma unroll
      for (int j = 0; j < 3; ++j) {
        f32x4 dd = (j == 0) ? d0 : (j == 1) ? d1 : d2;
        int part = cia[j] >> 2;
        int within = (cia[j] & 3) * 16 + cl;
        float bias = ipb[growa[j]];
        float scl = (part == 0) ? 0.17677669529663687f : 1.f;
        #pragma unroll
        for (int rg = 0; rg < 4; ++rg) {
          int row = kg * 4 + rg + 16 * ri0;
          if (row < 49) {
            unsigned short bv = f2bfu((dd[rg] + bias) * scl);
            if      (part == 0) q2[row * QK_STR + within] = bv;
            else if (part == 1) k2[row * QK_STR + within] = bv;
            else                vT2[within * VT_STR + row] = bv;
          }
        }
      }
    }
  };

  // ---- init: zero vT2 pad (token cols >=49 must stay 0), LN1 ----
  for (int i = tid; i < (64*VT_STR)/2; i += 512) ((unsigned*)(smem + VT_OFF))[i] = 0u;
  ln_pass(tokens, ln1g, ln1b);
  __syncthreads();

  f32x4 opacc[3][4];
  #pragma unroll
  for (int a = 0; a < 3; ++a)
    #pragma unroll
    for (int b = 0; b < 4; ++b) opacc[a][b] = f32x4{0.f,0.f,0.f,0.f};

  qkv(0);
  __syncthreads();

  const int hl = wv & 1, qci = wv >> 1;   // wave's (head-within-pair, q col-tile)

  for (int pr = 0; pr < 6; ++pr) {
    // ---- out-proj B prefetch: issue now, consumed in P_b (hidden under softmax)
    short8 Bo0[2], Bo1[2], Bo2[2];
    #pragma unroll
    for (int kt = 0; kt < 2; ++kt) {
      Bo0[kt] = loadW<WBF>(outw, wv*3 + 0, 48, pr*8 + kt*4, l,
                           (wv*3 + 0)*16 + cl, 384, pr*64 + kt*32 + kg*8);
      Bo1[kt] = loadW<WBF>(outw, wv*3 + 1, 48, pr*8 + kt*4, l,
                           (wv*3 + 1)*16 + cl, 384, pr*64 + kt*32 + kg*8);
      Bo2[kt] = loadW<WBF>(outw, wv*3 + 2, 48, pr*8 + kt*4, l,
                           (wv*3 + 2)*16 + cl, 384, pr*64 + kt*32 + kg*8);
    }

    // ---- P_a: scores (swapped: mfma(K,Q)) + in-register softmax + PV ----
    {
      short8 bq = *(const short8*)&q2[(16*qci + cl) * QK_STR + hl*32 + kg*8];
      f32x4 dsc[4];
      __builtin_amdgcn_s_setprio(1);
      #pragma unroll
      for (int kri = 0; kri < 4; ++kri) {
        short8 ak = *(const short8*)&k2[(16*kri + cl) * QK_STR + hl*32 + kg*8];
        f32x4 z{0.f,0.f,0.f,0.f};
        dsc[kri] = MFMA_B16(ak, bq, z);
      }
      __builtin_amdgcn_s_setprio(0);
      // lane (cl,kg) holds scores(k=16kri+4kg+r, q=16qci+cl); mask k>=49
      float ev[4][4];
      float mx = -1e30f;
      #pragma unroll
      for (int kri = 0; kri < 4; ++kri)
        #pragma unroll
        for (int r = 0; r < 4; ++r) {
          int kidx = 16*kri + 4*kg + r;
          float v = (kidx < 49) ? dsc[kri][r] : -1e30f;
          ev[kri][r] = v;
          mx = fmaxf(mx, v);
        }
      mx = fmaxf(mx, __shfl_xor(mx, 16));
      mx = fmaxf(mx, __shfl_xor(mx, 32));
      float sum = 0.f;
      #pragma unroll
      for (int kri = 0; kri < 4; ++kri)
        #pragma unroll
        for (int r = 0; r < 4; ++r) {
          float e = __expf(ev[kri][r] - mx);
          ev[kri][r] = e; sum += e;
        }
      sum += __shfl_xor(sum, 16);
      sum += __shfl_xor(sum, 32);
      float inv = 1.f / sum;
      unsigned pk[4][2];
      #pragma unroll
      for (int kri = 0; kri < 4; ++kri) {
        pk[kri][0] = pk2(ev[kri][0]*inv, ev[kri][1]*inv);
        pk[kri][1] = pk2(ev[kri][2]*inv, ev[kri][3]*inv);
      }
      // PV (swapped: mfma(vT, P)) -> oh^T; P B-frags built by shuffles
      f32x4 dot0{0.f,0.f,0.f,0.f}, dot1{0.f,0.f,0.f,0.f};
      const int sA = cl + 32 * (kg & 1);
      const bool hi = (kg >> 1) & 1;
      #pragma unroll
      for (int kt = 0; kt < 2; ++kt) {
        unsigned x0 = (unsigned)__shfl((int)pk[2*kt][0],   sA);
        unsigned x1 = (unsigned)__shfl((int)pk[2*kt][1],   sA);
        unsigned x2 = (unsigned)__shfl((int)pk[2*kt][0],   sA + 16);
        unsigned x3 = (unsigned)__shfl((int)pk[2*kt][1],   sA + 16);
        unsigned y0 = (unsigned)__shfl((int)pk[2*kt+1][0], sA);
        unsigned y1 = (unsigned)__shfl((int)pk[2*kt+1][1], sA);
        unsigned y2 = (unsigned)__shfl((int)pk[2*kt+1][0], sA + 16);
        unsigned y3 = (unsigned)__shfl((int)pk[2*kt+1][1], sA + 16);
        uint4 bu = make_uint4(hi ? y0 : x0, hi ? y1 : x1, hi ? y2 : x2, hi ? y3 : x3);
        short8 bfrag = *(short8*)&bu;
        short8 a0 = *(const short8*)&vT2[(hl*32 +  0 + cl) * VT_STR + kt*32 + kg*8];
        short8 a1 = *(const short8*)&vT2[(hl*32 + 16 + cl) * VT_STR + kt*32 + kg*8];
        __builtin_amdgcn_s_setprio(1);
        dot0 = MFMA_B16(a0, bfrag, dot0);
        dot1 = MFMA_B16(a1, bfrag, dot1);
        __builtin_amdgcn_s_setprio(0);
      }
      int q = 16*qci + cl;
      if (q < 49) {
        int base = q * OH_STR + hl*32 + kg*4;
        *(unsigned*)&oh[base     ] = pk2(dot0[0], dot0[1]);
        *(unsigned*)&oh[base +  2] = pk2(dot0[2], dot0[3]);
        *(unsigned*)&oh[base + 16] = pk2(dot1[0], dot1[1]);
        *(unsigned*)&oh[base + 18] = pk2(dot1[2], dot1[3]);
      }
    }
    __syncthreads();

    // ---- P_b: out-proj(pr) (K=64, both heads, prefetched B) + QKV(pr+1) ----
    {
      short8 ao[4][2];
      #pragma unroll
      for (int ri = 0; ri < 4; ++ri)
        #pragma unroll
        for (int kt = 0; kt < 2; ++kt)
          ao[ri][kt] = *(const short8*)&oh[(cl + 16*ri) * OH_STR + kt*32 + kg*8];
      __builtin_amdgcn_s_setprio(1);
      #pragma unroll
      for (int kt = 0; kt < 2; ++kt) {
        opacc[0][0] = MFMA_B16(ao[0][kt], Bo0[kt], opacc[0][0]);
        opacc[0][1] = MFMA_B16(ao[1][kt], Bo0[kt], opacc[0][1]);
        opacc[0][2] = MFMA_B16(ao[2][kt], Bo0[kt], opacc[0][2]);
        opacc[0][3] = MFMA_B16(ao[3][kt], Bo0[kt], opacc[0][3]);
        opacc[1][0] = MFMA_B16(ao[0][kt], Bo1[kt], opacc[1][0]);
        opacc[1][1] = MFMA_B16(ao[1][kt], Bo1[kt], opacc[1][1]);
        opacc[1][2] = MFMA_B16(ao[2][kt], Bo1[kt], opacc[1][2]);
        opacc[1][3] = MFMA_B16(ao[3][kt], Bo1[kt], opacc[1][3]);
        opacc[2][0] = MFMA_B16(ao[0][kt], Bo2[kt], opacc[2][0]);
        opacc[2][1] = MFMA_B16(ao[1][kt], Bo2[kt], opacc[2][1]);
        opacc[2][2] = MFMA_B16(ao[2][kt], Bo2[kt], opacc[2][2]);
        opacc[2][3] = MFMA_B16(ao[3][kt], Bo2[kt], opacc[2][3]);
      }
      __builtin_amdgcn_s_setprio(0);
      if (pr < 5) qkv(pr + 1);
    }
    __syncthreads();
  }

  // ---- win = tokens + attn + out_b -> out ----
  #pragma unroll
  for (int cii = 0; cii < 3; ++cii) {
    int col = (wv*3 + cii) * 16 + cl;
    float ob = outb[col];
    #pragma unroll
    for (int ri = 0; ri < 4; ++ri) {
      #pragma unroll
      for (int rg = 0; rg < 4; ++rg) {
        int row = kg*4 + rg + 16*ri;
        if (row < 49) {
          size_t g = gidx(row, col);
          out[g] = tokens[g] + opacc[cii][ri][rg] + ob;
        }
      }
    }
  }
  __syncthreads();

  // ---- LN2 ----
  ln_pass(out, ln2g, ln2b);
  __syncthreads();

  // ---- MLP: double-buffered hid, MLP2(cc-1)+MLP1(cc) per phase ----
  f32x4 macc[3][4];
  #pragma unroll
  for (int a = 0; a < 3; ++a)
    #pragma unroll
    for (int b = 0; b < 4; ++b) macc[a][b] = f32x4{0.f,0.f,0.f,0.f};

  auto mlp1 = [&](int cc, unsigned short* hb) {
    int tile = cc * 8 + wv;
    int n = cc * 128 + wv * 16 + cl;
    f32x4 e0{0,0,0,0}, e1{0,0,0,0}, e2{0,0,0,0}, e3{0,0,0,0};
    __builtin_amdgcn_s_setprio(1);
    #pragma unroll
    for (int kt = 0; kt < 12; ++kt) {
      int k0 = kt * 32 + kg * 8;
      short8 bw = loadW<WBF>(w1, tile, 48, kt*4, l, n, 384, k0);
      short8 a0 = *(const short8*)&aln[(cl     ) * ALN_STR + k0];
      short8 a1 = *(const short8*)&aln[(cl + 16) * ALN_STR + k0];
      short8 a2 = *(const short8*)&aln[(cl + 32) * ALN_STR + k0];
      short8 a3 = *(const short8*)&aln[(cl + 48) * ALN_STR + k0];
      e0 = MFMA_B16(a0, bw, e0);
      e1 = MFMA_B16(a1, bw, e1);
      e2 = MFMA_B16(a2, bw, e2);
      e3 = MFMA_B16(a3, bw, e3);
    }
    __builtin_amdgcn_s_setprio(0);
    float bb = b1[n];
    #pragma unroll
    for (int ri = 0; ri < 4; ++ri) {
      f32x4 ee = (ri == 0) ? e0 : (ri == 1) ? e1 : (ri == 2) ? e2 : e3;
      #pragma unroll
      for (int rg = 0; rg < 4; ++rg) {
        int row = kg*4 + rg + 16*ri;
        if (row < 49) {
          float x = ee[rg] + bb;
          float gl = 0.5f * x * (1.f + erff(x * 0.70710678118654752f));
          hb[row * HID_STR + wv*16 + cl] = f2bfu(gl);
        }
      }
    }
  };
  auto mlp2 = [&](int cc, const unsigned short* hb) {
    __builtin_amdgcn_s_setprio(1);
    #pragma unroll
    for (int kt = 0; kt < 4; ++kt) {
      int k0 = kt * 32 + kg * 8;
      short8 h0_ = *(const short8*)&hb[(cl     ) * HID_STR + k0];
      short8 h1_ = *(const short8*)&hb[(cl + 16) * HID_STR + k0];
      short8 h2_ = *(const short8*)&hb[(cl + 32) * HID_STR + k0];
      short8 h3_ = *(const short8*)&hb[(cl + 48) * HID_STR + k0];
      #pragma unroll
      for (int cii = 0; cii < 3; ++cii) {
        short8 bw = loadW<WBF>(w2, wv*3 + cii, 192, cc*16 + kt*4, l,
                               (wv*3 + cii)*16 + cl, 1536, cc*128 + k0);
        macc[cii][0] = MFMA_B16(h0_, bw, macc[cii][0]);
        macc[cii][1] = MFMA_B16(h1_, bw, macc[cii][1]);
        macc[cii][2] = MFMA_B16(h2_, bw, macc[cii][2]);
        macc[cii][3] = MFMA_B16(h3_, bw, macc[cii][3]);
      }
    }
    __builtin_amdgcn_s_setprio(0);
  };

  mlp1(0, hid0);
  __syncthreads();
  for (int cc = 1; cc < 12; ++cc) {
    mlp2(cc - 1, ((cc - 1) & 1) ? hid1 : hid0);
    mlp1(cc, (cc & 1) ? hid1 : hid0);
    __syncthreads();
  }
  mlp2(11, hid1);

  // ---- final: out += mlp + b2 ----
  #pragma unroll
  for (int cii = 0; cii < 3; ++cii) {
    int col = (wv*3 + cii) * 16 + cl;
    float bb2 = b2[col];
    #pragma unroll
    for (int ri = 0; ri < 4; ++ri) {
      #pragma unroll
      for (int rg = 0; rg < 4; ++rg) {
        int row = kg*4 + rg + 16*ri;
        if (row < 49) {
          size_t g = gidx(row, col);
          out[g] = out[g] + macc[cii][ri][rg] + bb2;
        }
      }
    }
  }
}

// ws layout (bf16 elements): ipw[442368] | outw[147456] | w1[589824] | w2[589824]
#define WS_IPW  0
#define WS_OUTW 442368
#define WS_W1   589824
#define WS_W2   1179648
#define WS_TOT  1769472

extern "C" void kernel_launch(void* const* d_in, const int* in_sizes, int n_in,
                              void* d_out, int out_size, void* d_ws, size_t ws_size,
                              hipStream_t stream) {
  (void)in_sizes; (void)n_in; (void)out_size;
  const float* tokens = (const float*)d_in[0];
  const float* ipw  = (const float*)d_in[1];
  const float* ipb  = (const float*)d_in[2];
  const float* outw = (const float*)d_in[3];
  const float* outb = (const float*)d_in[4];
  const float* ln1g = (const float*)d_in[5];
  const float* ln1b = (const float*)d_in[6];
  const float* w1   = (const float*)d_in[7];
  const float* b1   = (const float*)d_in[8];
  const float* w2   = (const float*)d_in[9];
  const float* b2   = (const float*)d_in[10];
  const float* ln2g = (const float*)d_in[11];
  const float* ln2b = (const float*)d_in[12];
  float* out = (float*)d_out;

  bool wbf = (ws_size >= (size_t)WS_TOT * 2);
  if (wbf) {
    unsigned short* wsp = (unsigned short*)d_ws;
    hipLaunchKernelGGL(cvt_pack, dim3((442368+511)/512), dim3(512), 0, stream, ipw,  wsp + WS_IPW,  384,  442368);
    hipLaunchKernelGGL(cvt_pack, dim3((147456+511)/512), dim3(512), 0, stream, outw, wsp + WS_OUTW, 384,  147456);
    hipLaunchKernelGGL(cvt_pack, dim3((589824+511)/512), dim3(512), 0, stream, w1,   wsp + WS_W1,   384,  589824);
    hipLaunchKernelGGL(cvt_pack, dim3((589824+511)/512), dim3(512), 0, stream, w2,   wsp + WS_W2,   1536, 589824);
    (void)hipFuncSetAttribute((const void*)swin_mfma<true>,
                              hipFuncAttributeMaxDynamicSharedMemorySize, SMEM_BYTES);
    hipLaunchKernelGGL((swin_mfma<true>), dim3(1024), dim3(512), SMEM_BYTES, stream,
                       tokens, (const void*)(wsp + WS_IPW), ipb,
                       (const void*)(wsp + WS_OUTW), outb, ln1g, ln1b,
                       (const void*)(wsp + WS_W1), b1, (const void*)(wsp + WS_W2), b2,
                       ln2g, ln2b, out);
  } else {
    (void)hipFuncSetAttribute((const void*)swin_mfma<false>,
                              hipFuncAttributeMaxDynamicSharedMemorySize, SMEM_BYTES);
    hipLaunchKernelGGL((swin_mfma<false>), dim3(1024), dim3(512), SMEM_BYTES, stream,
                       tokens, (const void*)ipw, ipb, (const void*)outw, outb, ln1g, ln1b,
                       (const void*)w1, b1, (const void*)w2, b2, ln2g, ln2b, out);
  }
}

// Round 12
// 476.655 us; speedup vs baseline: 2.4996x; 1.0595x over previous
//
#include <hip/hip_runtime.h>
#include <hip/hip_bf16.h>
#include <math.h>

using short8 = __attribute__((ext_vector_type(8))) short;
using f32x4  = __attribute__((ext_vector_type(4))) float;

#define MFMA_B16(A,B,C) __builtin_amdgcn_mfma_f32_16x16x32_bf16((A),(B),(C),0,0,0)

// ---------------- LDS layout (bytes) ----------------
// aln [49][392]u16; q2/k2 [49][72]u16 (rows>=49 garbage: masked or discarded);
// vT2 [64][72]u16 (token cols>=49 zero-init, never overwritten); oh [64][72]u16
// (rows>=49 garbage -> discarded C rows). MLP: hid double-buffer [64][136]u16
// aliases q2..oh pool. Total 79 KiB -> 2 blocks/CU.
#define ALN_STR 392
#define Q2_OFF  38416
#define QK_STR  72
#define K2_OFF  45472
#define VT_OFF  52528
#define VT_STR  72
#define OH_OFF  61744
#define OH_STR  72
#define HID0_OFF 38416
#define HID1_OFF 55824
#define HID_STR 136
#define SMEM_BYTES 80896   // 79 KiB

__device__ __forceinline__ unsigned short f2bfu(float x) {   // RNE f32->bf16
  unsigned u = __float_as_uint(x);
  return (unsigned short)((u + 0x7fffu + ((u >> 16) & 1u)) >> 16);
}
__device__ __forceinline__ unsigned pk2(float a, float b) {
  return (unsigned)f2bfu(a) | ((unsigned)f2bfu(b) << 16);
}

// B-operand load. WBF: packed fragment layout [tile][kchunk][lane][8] bf16 ->
// one coalesced 16B/lane read. !WBF: gather from f32 row-major + convert.
template<bool WBF>
__device__ __forceinline__ short8 loadW(const void* base, int tile, int K8, int kcb,
                                        int l, int row, int ldk, int k0) {
  if constexpr (WBF) {
    return *(const short8*)((const unsigned short*)base +
                            (((size_t)(tile * K8 + kcb)) << 7) + l * 8);
  } else {
    const float* p = (const float*)base + (size_t)row * ldk + k0;
    float4 x = *(const float4*)p;
    float4 y = *(const float4*)(p + 4);
    short8 r;
    r[0]=(short)f2bfu(x.x); r[1]=(short)f2bfu(x.y); r[2]=(short)f2bfu(x.z); r[3]=(short)f2bfu(x.w);
    r[4]=(short)f2bfu(y.x); r[5]=(short)f2bfu(y.y); r[6]=(short)f2bfu(y.z); r[7]=(short)f2bfu(y.w);
    return r;
  }
}

// Repack f32 [rows][K] -> bf16 fragment order [tile][kc][r16][8].
__global__ void cvt_pack(const float* __restrict__ src, unsigned short* __restrict__ dst,
                         int K, int n) {
  int K8 = K >> 3;
  int i = blockIdx.x * blockDim.x + threadIdx.x;
  if (i >= n) return;
  int e = i & 7;
  int idx = i >> 3;
  int r = idx & 15; idx >>= 4;
  int kc = idx % K8, ci = idx / K8;
  dst[i] = f2bfu(src[(size_t)(ci * 16 + r) * K + kc * 8 + e]);
}

template<bool WBF>
__global__ __launch_bounds__(512, 4)
void swin_mfma(const float* __restrict__ tokens,
               const void* __restrict__ ipw,  const float* __restrict__ ipb,
               const void* __restrict__ outw, const float* __restrict__ outb,
               const float* __restrict__ ln1g, const float* __restrict__ ln1b,
               const void* __restrict__ w1,   const float* __restrict__ b1,
               const void* __restrict__ w2,   const float* __restrict__ b2,
               const float* __restrict__ ln2g, const float* __restrict__ ln2b,
               float* __restrict__ out)
{
  extern __shared__ char smem[];
  unsigned short* aln  = (unsigned short*)smem;
  unsigned short* q2   = (unsigned short*)(smem + Q2_OFF);
  unsigned short* k2   = (unsigned short*)(smem + K2_OFF);
  unsigned short* vT2  = (unsigned short*)(smem + VT_OFF);
  unsigned short* oh   = (unsigned short*)(smem + OH_OFF);
  unsigned short* hid0 = (unsigned short*)(smem + HID0_OFF);
  unsigned short* hid1 = (unsigned short*)(smem + HID1_OFF);

  const int tid = threadIdx.x;
  const int l  = tid & 63, wv = tid >> 6;
  const int cl = l & 15,  kg = l >> 4;
  const int wid = blockIdx.x;
  const int iw = wid & 7, ih = (wid >> 3) & 7, bt = wid >> 6;

  auto gidx = [&](int r, int c) -> size_t {
    int wi = r / 7, wj = r - wi * 7;
    return ((size_t)bt * 3136 + (size_t)((ih*7 + wi) * 56 + iw*7 + wj)) * 384 + c;
  };

  auto ln_pass = [&](const float* src, const float* gw, const float* gb) {
    int grp = tid >> 3, lj = tid & 7;
    if (grp < 49) {
      size_t base = gidx(grp, 0);
      float4 xv[12];
      float sx = 0.f, sxx = 0.f;
      #pragma unroll
      for (int k = 0; k < 12; ++k) {
        xv[k] = *(const float4*)&src[base + (lj + 8*k) * 4];
        sx  += xv[k].x + xv[k].y + xv[k].z + xv[k].w;
        sxx += xv[k].x*xv[k].x + xv[k].y*xv[k].y + xv[k].z*xv[k].z + xv[k].w*xv[k].w;
      }
      #pragma unroll
      for (int d = 1; d < 8; d <<= 1) { sx += __shfl_xor(sx, d, 8); sxx += __shfl_xor(sxx, d, 8); }
      float mean = sx * (1.f/384.f);
      float rs = rsqrtf(sxx * (1.f/384.f) - mean*mean + 1e-5f);
      unsigned short* arow = aln + grp * ALN_STR;
      #pragma unroll
      for (int k = 0; k < 12; ++k) {
        int c = (lj + 8*k) * 4;
        float4 gv = *(const float4*)&gw[c];
        float4 bv = *(const float4*)&gb[c];
        unsigned u0 = pk2((xv[k].x-mean)*rs*gv.x + bv.x, (xv[k].y-mean)*rs*gv.y + bv.y);
        unsigned u1 = pk2((xv[k].z-mean)*rs*gv.z + bv.z, (xv[k].w-mean)*rs*gv.w + bv.w);
        *(uint2*)&arow[c] = make_uint2(u0, u1);
      }
    }
  };

  const int ri0 = wv & 3, chalf = wv >> 2;
  const int arow0 = (cl + 16 * ri0) * ALN_STR;

  // QKV for head pair pr: writes q2/k2/vT2 (rows<49 only).
  auto qkv = [&](int pr) {
    #pragma unroll
    for (int half = 0; half < 2; ++half) {
      int cia[3], tilea[3], growa[3];
      #pragma unroll
      for (int j = 0; j < 3; ++j) {
        int ci = chalf + 2 * (half * 3 + j);
        int part = ci >> 2, wt = ci & 3;
        cia[j] = ci;
        tilea[j] = part * 24 + pr * 4 + wt;
        growa[j] = part * 384 + pr * 64 + wt * 16 + cl;
      }
      f32x4 d0{0,0,0,0}, d1{0,0,0,0}, d2{0,0,0,0};
      #pragma unroll
      for (int kt = 0; kt < 12; ++kt) {
        int k0 = kt * 32 + kg * 8;
        short8 a = *(const short8*)&aln[arow0 + k0];
        short8 b0 = loadW<WBF>(ipw, tilea[0], 48, kt*4, l, growa[0], 384, k0);
        short8 b1 = loadW<WBF>(ipw, tilea[1], 48, kt*4, l, growa[1], 384, k0);
        short8 b2 = loadW<WBF>(ipw, tilea[2], 48, kt*4, l, growa[2], 384, k0);
        d0 = MFMA_B16(a, b0, d0);
        d1 = MFMA_B16(a, b1, d1);
        d2 = MFMA_B16(a, b2, d2);
      }
      #pragma unroll
      for (int j = 0; j < 3; ++j) {
        f32x4 dd = (j == 0) ? d0 : (j == 1) ? d1 : d2;
        int part = cia[j] >> 2;
        int within = (cia[j] & 3) * 16 + cl;
        float bias = ipb[growa[j]];
        float scl = (part == 0) ? 0.17677669529663687f : 1.f;
        #pragma unroll
        for (int rg = 0; rg < 4; ++rg) {
          int row = kg * 4 + rg + 16 * ri0;
          if (row < 49) {
            unsigned short bv = f2bfu((dd[rg] + bias) * scl);
            if      (part == 0) q2[row * QK_STR + within] = bv;
            else if (part == 1) k2[row * QK_STR + within] = bv;
            else                vT2[within * VT_STR + row] = bv;
          }
        }
      }
    }
  };

  // ---- init: zero vT2 pad (token cols >=49 must stay 0), LN1 ----
  for (int i = tid; i < (64*VT_STR)/2; i += 512) ((unsigned*)(smem + VT_OFF))[i] = 0u;
  ln_pass(tokens, ln1g, ln1b);
  __syncthreads();

  f32x4 opacc[3][4];
  #pragma unroll
  for (int a = 0; a < 3; ++a)
    #pragma unroll
    for (int b = 0; b < 4; ++b) opacc[a][b] = f32x4{0.f,0.f,0.f,0.f};

  qkv(0);
  __syncthreads();

  const int hl = wv & 1, qci = wv >> 1;   // wave's (head-within-pair, q col-tile)

  for (int pr = 0; pr < 6; ++pr) {
    // ---- P_a: scores (swapped: mfma(K,Q)) + in-register softmax + PV ----
    {
      short8 bq = *(const short8*)&q2[(16*qci + cl) * QK_STR + hl*32 + kg*8];
      f32x4 dsc[4];
      #pragma unroll
      for (int kri = 0; kri < 4; ++kri) {
        short8 ak = *(const short8*)&k2[(16*kri + cl) * QK_STR + hl*32 + kg*8];
        f32x4 z{0.f,0.f,0.f,0.f};
        dsc[kri] = MFMA_B16(ak, bq, z);
      }
      // lane (cl,kg) holds scores(k=16kri+4kg+r, q=16qci+cl); mask k>=49
      float ev[4][4];
      float mx = -1e30f;
      #pragma unroll
      for (int kri = 0; kri < 4; ++kri)
        #pragma unroll
        for (int r = 0; r < 4; ++r) {
          int kidx = 16*kri + 4*kg + r;
          float v = (kidx < 49) ? dsc[kri][r] : -1e30f;
          ev[kri][r] = v;
          mx = fmaxf(mx, v);
        }
      mx = fmaxf(mx, __shfl_xor(mx, 16));
      mx = fmaxf(mx, __shfl_xor(mx, 32));
      float sum = 0.f;
      #pragma unroll
      for (int kri = 0; kri < 4; ++kri)
        #pragma unroll
        for (int r = 0; r < 4; ++r) {
          float e = __expf(ev[kri][r] - mx);
          ev[kri][r] = e; sum += e;
        }
      sum += __shfl_xor(sum, 16);
      sum += __shfl_xor(sum, 32);
      float inv = 1.f / sum;
      unsigned pk[4][2];
      #pragma unroll
      for (int kri = 0; kri < 4; ++kri) {
        pk[kri][0] = pk2(ev[kri][0]*inv, ev[kri][1]*inv);
        pk[kri][1] = pk2(ev[kri][2]*inv, ev[kri][3]*inv);
      }
      // PV (swapped: mfma(vT, P)) -> oh^T; P B-frags built by shuffles
      f32x4 dot0{0.f,0.f,0.f,0.f}, dot1{0.f,0.f,0.f,0.f};
      const int sA = cl + 32 * (kg & 1);
      const bool hi = (kg >> 1) & 1;
      #pragma unroll
      for (int kt = 0; kt < 2; ++kt) {
        unsigned x0 = (unsigned)__shfl((int)pk[2*kt][0],   sA);
        unsigned x1 = (unsigned)__shfl((int)pk[2*kt][1],   sA);
        unsigned x2 = (unsigned)__shfl((int)pk[2*kt][0],   sA + 16);
        unsigned x3 = (unsigned)__shfl((int)pk[2*kt][1],   sA + 16);
        unsigned y0 = (unsigned)__shfl((int)pk[2*kt+1][0], sA);
        unsigned y1 = (unsigned)__shfl((int)pk[2*kt+1][1], sA);
        unsigned y2 = (unsigned)__shfl((int)pk[2*kt+1][0], sA + 16);
        unsigned y3 = (unsigned)__shfl((int)pk[2*kt+1][1], sA + 16);
        uint4 bu = make_uint4(hi ? y0 : x0, hi ? y1 : x1, hi ? y2 : x2, hi ? y3 : x3);
        short8 bfrag = *(short8*)&bu;
        short8 a0 = *(const short8*)&vT2[(hl*32 +  0 + cl) * VT_STR + kt*32 + kg*8];
        short8 a1 = *(const short8*)&vT2[(hl*32 + 16 + cl) * VT_STR + kt*32 + kg*8];
        dot0 = MFMA_B16(a0, bfrag, dot0);
        dot1 = MFMA_B16(a1, bfrag, dot1);
      }
      int q = 16*qci + cl;
      if (q < 49) {
        int base = q * OH_STR + hl*32 + kg*4;
        *(unsigned*)&oh[base     ] = pk2(dot0[0], dot0[1]);
        *(unsigned*)&oh[base +  2] = pk2(dot0[2], dot0[3]);
        *(unsigned*)&oh[base + 16] = pk2(dot1[0], dot1[1]);
        *(unsigned*)&oh[base + 18] = pk2(dot1[2], dot1[3]);
      }
    }
    __syncthreads();

    // ---- P_b: out-proj(pr) (K=64, both heads) + QKV(pr+1) ----
    {
      short8 ao[4][2];
      #pragma unroll
      for (int ri = 0; ri < 4; ++ri)
        #pragma unroll
        for (int kt = 0; kt < 2; ++kt)
          ao[ri][kt] = *(const short8*)&oh[(cl + 16*ri) * OH_STR + kt*32 + kg*8];
      #pragma unroll
      for (int cii = 0; cii < 3; ++cii) {
        #pragma unroll
        for (int kt = 0; kt < 2; ++kt) {
          short8 bw = loadW<WBF>(outw, wv*3 + cii, 48, pr*8 + kt*4, l,
                                 (wv*3 + cii)*16 + cl, 384, pr*64 + kt*32 + kg*8);
          opacc[cii][0] = MFMA_B16(ao[0][kt], bw, opacc[cii][0]);
          opacc[cii][1] = MFMA_B16(ao[1][kt], bw, opacc[cii][1]);
          opacc[cii][2] = MFMA_B16(ao[2][kt], bw, opacc[cii][2]);
          opacc[cii][3] = MFMA_B16(ao[3][kt], bw, opacc[cii][3]);
        }
      }
      if (pr < 5) qkv(pr + 1);
    }
    __syncthreads();
  }

  // ---- win = tokens + attn + out_b -> out; ALSO kept in regs for final ----
  float winr[3][4][4];
  #pragma unroll
  for (int cii = 0; cii < 3; ++cii) {
    int col = (wv*3 + cii) * 16 + cl;
    float ob = outb[col];
    #pragma unroll
    for (int ri = 0; ri < 4; ++ri) {
      #pragma unroll
      for (int rg = 0; rg < 4; ++rg) {
        int row = kg*4 + rg + 16*ri;
        if (row < 49) {
          size_t g = gidx(row, col);
          float v = tokens[g] + opacc[cii][ri][rg] + ob;
          winr[cii][ri][rg] = v;
          out[g] = v;
        }
      }
    }
  }
  __syncthreads();

  // ---- LN2 ----
  ln_pass(out, ln2g, ln2b);
  __syncthreads();

  // ---- MLP: double-buffered hid, MLP2(cc-1)+MLP1(cc) per phase ----
  f32x4 macc[3][4];
  #pragma unroll
  for (int a = 0; a < 3; ++a)
    #pragma unroll
    for (int b = 0; b < 4; ++b) macc[a][b] = f32x4{0.f,0.f,0.f,0.f};

  auto mlp1 = [&](int cc, unsigned short* hb) {
    int tile = cc * 8 + wv;
    int n = cc * 128 + wv * 16 + cl;
    f32x4 e0{0,0,0,0}, e1{0,0,0,0}, e2{0,0,0,0}, e3{0,0,0,0};
    #pragma unroll
    for (int kt = 0; kt < 12; ++kt) {
      int k0 = kt * 32 + kg * 8;
      short8 bw = loadW<WBF>(w1, tile, 48, kt*4, l, n, 384, k0);
      short8 a0 = *(const short8*)&aln[(cl     ) * ALN_STR + k0];
      short8 a1 = *(const short8*)&aln[(cl + 16) * ALN_STR + k0];
      short8 a2 = *(const short8*)&aln[(cl + 32) * ALN_STR + k0];
      short8 a3 = *(const short8*)&aln[(cl + 48) * ALN_STR + k0];
      e0 = MFMA_B16(a0, bw, e0);
      e1 = MFMA_B16(a1, bw, e1);
      e2 = MFMA_B16(a2, bw, e2);
      e3 = MFMA_B16(a3, bw, e3);
    }
    float bb = b1[n];
    #pragma unroll
    for (int ri = 0; ri < 4; ++ri) {
      f32x4 ee = (ri == 0) ? e0 : (ri == 1) ? e1 : (ri == 2) ? e2 : e3;
      #pragma unroll
      for (int rg = 0; rg < 4; ++rg) {
        int row = kg*4 + rg + 16*ri;
        if (row < 49) {
          float x = ee[rg] + bb;
          float gl = 0.5f * x * (1.f + erff(x * 0.70710678118654752f));
          hb[row * HID_STR + wv*16 + cl] = f2bfu(gl);
        }
      }
    }
  };
  auto mlp2 = [&](int cc, const unsigned short* hb) {
    #pragma unroll
    for (int kt = 0; kt < 4; ++kt) {
      int k0 = kt * 32 + kg * 8;
      short8 h0_ = *(const short8*)&hb[(cl     ) * HID_STR + k0];
      short8 h1_ = *(const short8*)&hb[(cl + 16) * HID_STR + k0];
      short8 h2_ = *(const short8*)&hb[(cl + 32) * HID_STR + k0];
      short8 h3_ = *(const short8*)&hb[(cl + 48) * HID_STR + k0];
      #pragma unroll
      for (int cii = 0; cii < 3; ++cii) {
        short8 bw = loadW<WBF>(w2, wv*3 + cii, 192, cc*16 + kt*4, l,
                               (wv*3 + cii)*16 + cl, 1536, cc*128 + k0);
        macc[cii][0] = MFMA_B16(h0_, bw, macc[cii][0]);
        macc[cii][1] = MFMA_B16(h1_, bw, macc[cii][1]);
        macc[cii][2] = MFMA_B16(h2_, bw, macc[cii][2]);
        macc[cii][3] = MFMA_B16(h3_, bw, macc[cii][3]);
      }
    }
  };

  mlp1(0, hid0);
  __syncthreads();
  for (int cc = 1; cc < 12; ++cc) {
    mlp2(cc - 1, ((cc - 1) & 1) ? hid1 : hid0);
    mlp1(cc, (cc & 1) ? hid1 : hid0);
    __syncthreads();
  }
  mlp2(11, hid1);

  // ---- final: out = winr + mlp + b2 (pure store, no re-read) ----
  #pragma unroll
  for (int cii = 0; cii < 3; ++cii) {
    int col = (wv*3 + cii) * 16 + cl;
    float bb2 = b2[col];
    #pragma unroll
    for (int ri = 0; ri < 4; ++ri) {
      #pragma unroll
      for (int rg = 0; rg < 4; ++rg) {
        int row = kg*4 + rg + 16*ri;
        if (row < 49) {
          size_t g = gidx(row, col);
          out[g] = winr[cii][ri][rg] + macc[cii][ri][rg] + bb2;
        }
      }
    }
  }
}

// ws layout (bf16 elements): ipw[442368] | outw[147456] | w1[589824] | w2[589824]
#define WS_IPW  0
#define WS_OUTW 442368
#define WS_W1   589824
#define WS_W2   1179648
#define WS_TOT  1769472

extern "C" void kernel_launch(void* const* d_in, const int* in_sizes, int n_in,
                              void* d_out, int out_size, void* d_ws, size_t ws_size,
                              hipStream_t stream) {
  (void)in_sizes; (void)n_in; (void)out_size;
  const float* tokens = (const float*)d_in[0];
  const float* ipw  = (const float*)d_in[1];
  const float* ipb  = (const float*)d_in[2];
  const float* outw = (const float*)d_in[3];
  const float* outb = (const float*)d_in[4];
  const float* ln1g = (const float*)d_in[5];
  const float* ln1b = (const float*)d_in[6];
  const float* w1   = (const float*)d_in[7];
  const float* b1   = (const float*)d_in[8];
  const float* w2   = (const float*)d_in[9];
  const float* b2   = (const float*)d_in[10];
  const float* ln2g = (const float*)d_in[11];
  const float* ln2b = (const float*)d_in[12];
  float* out = (float*)d_out;

  bool wbf = (ws_size >= (size_t)WS_TOT * 2);
  if (wbf) {
    unsigned short* wsp = (unsigned short*)d_ws;
    hipLaunchKernelGGL(cvt_pack, dim3((442368+511)/512), dim3(512), 0, stream, ipw,  wsp + WS_IPW,  384,  442368);
    hipLaunchKernelGGL(cvt_pack, dim3((147456+511)/512), dim3(512), 0, stream, outw, wsp + WS_OUTW, 384,  147456);
    hipLaunchKernelGGL(cvt_pack, dim3((589824+511)/512), dim3(512), 0, stream, w1,   wsp + WS_W1,   384,  589824);
    hipLaunchKernelGGL(cvt_pack, dim3((589824+511)/512), dim3(512), 0, stream, w2,   wsp + WS_W2,   1536, 589824);
    (void)hipFuncSetAttribute((const void*)swin_mfma<true>,
                              hipFuncAttributeMaxDynamicSharedMemorySize, SMEM_BYTES);
    hipLaunchKernelGGL((swin_mfma<true>), dim3(1024), dim3(512), SMEM_BYTES, stream,
                       tokens, (const void*)(wsp + WS_IPW), ipb,
                       (const void*)(wsp + WS_OUTW), outb, ln1g, ln1b,
                       (const void*)(wsp + WS_W1), b1, (const void*)(wsp + WS_W2), b2,
                       ln2g, ln2b, out);
  } else {
    (void)hipFuncSetAttribute((const void*)swin_mfma<false>,
                              hipFuncAttributeMaxDynamicSharedMemorySize, SMEM_BYTES);
    hipLaunchKernelGGL((swin_mfma<false>), dim3(1024), dim3(512), SMEM_BYTES, stream,
                       tokens, (const void*)ipw, ipb, (const void*)outw, outb, ln1g, ln1b,
                       (const void*)w1, b1, (const void*)w2, b2, ln2g, ln2b, out);
  }
}